// Round 7
// baseline (330.583 us; speedup 1.0000x reference)
//
#include <hip/hip_runtime.h>
#include <hip/hip_bf16.h>
#include <math.h>

#define B_  4
#define S_  2048
#define H_  512
#define NH_ 8
#define D_  64

typedef __attribute__((ext_vector_type(8))) short bf16x8;   // 8 bf16 = 4 VGPR
typedef __attribute__((ext_vector_type(4))) float f32x4;
typedef __attribute__((ext_vector_type(16))) float f32x16;
#define MFMA16(a, b, c) __builtin_amdgcn_mfma_f32_16x16x32_bf16(a, b, c, 0, 0, 0)
#define MFMA32(a, b, c) __builtin_amdgcn_mfma_f32_32x32x16_bf16(a, b, c, 0, 0, 0)

__device__ __forceinline__ unsigned short f2bf(float f) {
    union { float f; unsigned int i; } x; x.f = f;
    unsigned int i = x.i;
    i += 0x7fffu + ((i >> 16) & 1u);
    return (unsigned short)(i >> 16);
}
// packed fp32 pair -> bf16 pair (RNE), lo in low 16 bits
__device__ __forceinline__ unsigned int pk2(float lo, float hi) {
    union { __hip_bfloat162 h; unsigned int u; } c;
    c.h = __float22bfloat162_rn(make_float2(lo, hi));
    return c.u;
}
// async global->LDS, 16 B per lane; lds ptr must be wave-uniform
__device__ __forceinline__ void gl_lds16(const void* g, void* l) {
    __builtin_amdgcn_global_load_lds(
        (const __attribute__((address_space(1))) unsigned int*)g,
        (__attribute__((address_space(3))) unsigned int*)l, 16, 0, 0);
}

// ---------------------------------------------------------------------------
// Weight prep: transpose+convert 512x512 fp32 W -> bf16 Wt[n][k] (n-major).
// ---------------------------------------------------------------------------
__global__ __launch_bounds__(256) void prep_w(
    const float* __restrict__ W0, const float* __restrict__ W1,
    const float* __restrict__ W2, const float* __restrict__ W3,
    unsigned short* __restrict__ Wt)
{
    const float* Ws[4] = {W0, W1, W2, W3};
    const float* W = Ws[blockIdx.z];
    unsigned short* Y = Wt + (size_t)blockIdx.z * H_ * H_;
    __shared__ float Tl[64][68];
    const int t = threadIdx.x;
    const int k0 = blockIdx.y * 64, n0 = blockIdx.x * 64;
    #pragma unroll
    for (int i = 0; i < 4; ++i) {
        const int e = (t + 256 * i) * 4;
        const int r = e >> 6, c = e & 63;
        const float4 a = *(const float4*)(W + (size_t)(k0 + r) * H_ + n0 + c);
        Tl[c + 0][r] = a.x; Tl[c + 1][r] = a.y;
        Tl[c + 2][r] = a.z; Tl[c + 3][r] = a.w;
    }
    __syncthreads();
    #pragma unroll
    for (int i = 0; i < 4; ++i) {
        const int e = (t + 256 * i) * 4;
        const int n = e >> 6, c = e & 63;
        uint2 p;
        p.x = pk2(Tl[n][c + 0], Tl[n][c + 1]);
        p.y = pk2(Tl[n][c + 2], Tl[n][c + 3]);
        *(uint2*)(Y + (size_t)(n0 + n) * H_ + k0 + c) = p;
    }
}

// ---------------------------------------------------------------------------
// Fused projections v4 -- LOAD-BALANCED z:
//   z=0: Q       128-row tile, 8 K-steps,  32 MFMA/step
//   z=1: K-dual  64-row tile (rows x*128..+64),   16 K-steps, 16 MFMA/step
//   z=2: K-dual  64-row tile (rows x*128+64..+128),16 K-steps, 16 MFMA/step
//   z=3: V       128-row tile, 8 K-steps, transposed epilogue
// Every block does exactly 256 MFMA-units -> no idle tail (was: z=K blocks
// 2x the work of Q/V -> ~33% of proj was drained-wave tail).
// Grid (64,4,4) = 1024 blocks = 4 blocks/CU (LDS 34KB, VGPR<=128).
// Accumulation order per output element is identical to the R3 version.
// ---------------------------------------------------------------------------
__global__ __launch_bounds__(256, 4) void proj_all(
    const float* __restrict__ q,  const float* __restrict__ k,
    const float* __restrict__ v,  const float* __restrict__ k_b,
    const unsigned short* __restrict__ Wt,
    const float* __restrict__ bq, const float* __restrict__ bk,
    const float* __restrict__ bkb,const float* __restrict__ bv,
    unsigned short* __restrict__ Qf, unsigned short* __restrict__ Kf,
    unsigned short* __restrict__ Vf)
{
    __shared__ __align__(16) unsigned short LB[17408];
    unsigned short* As = LB;            // up to 8192 halfs ([128][64] swz)
    unsigned short* Bs = LB + 8192;     // 8192 halfs ([128][64] swz)

    const int z = blockIdx.z;
    const bool KD = (z == 1) || (z == 2);   // K-dual slice
    const bool VT = (z == 3);
    const size_t WSZ = (size_t)H_ * H_;

    const float *X1, *X2p = nullptr, *bias1, *bias2p = nullptr;
    const unsigned short *W1, *W2p = nullptr;
    unsigned short* Y;
    if (z == 0)      { X1 = q; W1 = Wt;           bias1 = bq; Y = Qf; }
    else if (KD)     { X1 = k; W1 = Wt + WSZ;     bias1 = bk;
                       X2p = k_b; W2p = Wt + 2 * WSZ; bias2p = bkb; Y = Kf; }
    else             { X1 = v; W1 = Wt + 3 * WSZ; bias1 = bv; Y = Vf; }

    const int t = threadIdx.x;
    const int w = t >> 6, lane = t & 63;
    const int quad = lane >> 4, l15 = lane & 15;
    const int wr = w >> 1, wc = w & 1;
    const int rhalf = KD ? 32 : 64;                 // rows per wave-row-half
    const int RI = KD ? 2 : 4;                      // row fragments per wave
    const int nA = KD ? 4 : 8;                      // float4 loads per thread
    const int m0 = blockIdx.x * 128 + (KD ? (z - 1) * 64 : 0);
    const int n0 = blockIdx.y * 128;
    const int NS = KD ? 16 : 8;

    const f32x4 zero = {0.f, 0.f, 0.f, 0.f};
    f32x4 acc[4][4];
    #pragma unroll
    for (int i = 0; i < 4; ++i)
        #pragma unroll
        for (int j = 0; j < 4; ++j) acc[i][j] = zero;

    for (int s = 0; s < NS; ++s) {
        const float* Xp = (s >= 8) ? X2p : X1;
        const unsigned short* Wp = (s >= 8) ? W2p : W1;
        const int kb0 = (s & 7) * 64;
        __syncthreads();
        // ---- B tile 128n x 64k bf16: async gload_lds, pre-swizzled source
        #pragma unroll
        for (int i = 0; i < 4; ++i) {
            const int c = w * 4 + i;
            const int u = c * 64 + lane;
            const int row = u >> 3;
            const int sc  = ((u & 7) ^ (row & 7)) << 3;
            gl_lds16(Wp + (size_t)(n0 + row) * H_ + kb0 + sc, Bs + c * 512);
        }
        // ---- A tile rows x 64k fp32 -> bf16, swizzled write
        float4 av[8];
        #pragma unroll
        for (int i = 0; i < 8; ++i)
            if (i < nA) {
                const int e = (t + 256 * i) * 4;
                av[i] = *(const float4*)(Xp + (size_t)(m0 + (e >> 6)) * H_ + kb0 + (e & 63));
            }
        #pragma unroll
        for (int i = 0; i < 8; ++i)
            if (i < nA) {
                const int e = (t + 256 * i) * 4;
                const int row = e >> 6, kc = e & 63;
                uint2 p; p.x = pk2(av[i].x, av[i].y); p.y = pk2(av[i].z, av[i].w);
                *(uint2*)&As[row * 64 + ((((kc >> 3) ^ (row & 7)) << 3) | (kc & 7))] = p;
            }
        __syncthreads();
        #pragma unroll
        for (int ks = 0; ks < 2; ++ks) {
            bf16x8 af[4], bfr[4];
            #pragma unroll
            for (int i = 0; i < 4; ++i)
                if (i < RI) {
                    const int row = wr * rhalf + i * 16 + l15;
                    af[i] = *(const bf16x8*)&As[row * 64 +
                                (((ks * 4 + quad) ^ (row & 7)) << 3)];
                }
            #pragma unroll
            for (int j = 0; j < 4; ++j) {
                const int nrw = wc * 64 + j * 16 + l15;
                bfr[j] = *(const bf16x8*)&Bs[nrw * 64 +
                            (((ks * 4 + quad) ^ (nrw & 7)) << 3)];
            }
            #pragma unroll
            for (int i = 0; i < 4; ++i)
                if (i < RI)
                    #pragma unroll
                    for (int j = 0; j < 4; ++j)
                        acc[i][j] = MFMA16(af[i], bfr[j], acc[i][j]);
        }
    }

    const int bb = m0 >> 11, s0 = m0 & (S_ - 1);
    if (!VT) {
        #pragma unroll
        for (int i = 0; i < 4; ++i)
            if (i < RI)
                #pragma unroll
                for (int r = 0; r < 4; ++r) {
                    const int s = s0 + wr * rhalf + i * 16 + quad * 4 + r;
                    #pragma unroll
                    for (int j = 0; j < 4; ++j) {
                        const int nn = n0 + wc * 64 + j * 16 + l15;
                        const int h = nn >> 6, d = nn & 63;
                        float val = acc[i][j][r] + bias1[nn];
                        if (KD) val += bias2p[nn];
                        Y[(((size_t)bb * NH_ + h) * S_ + s) * D_ + d] = f2bf(val);
                    }
                }
    } else {
        // transposed [b,h,d,s] epilogue (z=3 only, 128-row tile)
        __syncthreads();
        #pragma unroll
        for (int i = 0; i < 4; ++i)
            #pragma unroll
            for (int r = 0; r < 4; ++r) {
                const int ml = wr * 64 + i * 16 + quad * 4 + r;
                #pragma unroll
                for (int j = 0; j < 4; ++j) {
                    const int nl = wc * 64 + j * 16 + l15;
                    LB[nl * 136 + ml] = f2bf(acc[i][j][r] + bias1[n0 + nl]);
                }
            }
        __syncthreads();
        const int nr = t >> 1, half = t & 1;
        const int nn = n0 + nr, h = nn >> 6, d = nn & 63;
        const size_t vbase = (((size_t)bb * NH_ + h) * D_ + d) * S_ + s0 + half * 64;
        #pragma unroll
        for (int i = 0; i < 16; ++i)
            *(ushort4*)(Y + vbase + i * 4) =
                *(const ushort4*)&LB[nr * 136 + half * 64 + i * 4];
    }
}

// ---------------------------------------------------------------------------
// MFMA flash attention v5 (unchanged control): key-split waves + lsum on the
// MFMA pipe via ones-MFMA.
// ---------------------------------------------------------------------------
__global__ __launch_bounds__(256, 4) void attn_mfma(
    unsigned short* QHd,
    const unsigned short* __restrict__ Kh, const unsigned short* __restrict__ Vt,
    const int* __restrict__ mask)
{
    const int b = blockIdx.z, h = blockIdx.y;
    const int q0 = blockIdx.x * 64;
    const int t = threadIdx.x;
    const int w = t >> 6, lane = t & 63;
    const int hi = lane >> 5, l31 = lane & 31;
    const int qg = w & 1, kh = w >> 1;

    __shared__ __align__(16) unsigned short KsL[2 * 4096];  // [2][64 key][64 d] swz
    __shared__ __align__(16) unsigned short VsL[2 * 4096];  // [2][64 d][64 key] swz
    __shared__ float mskf[S_];                              // -1e9 / 0 per key

    const size_t head = ((size_t)b * NH_ + h) * S_;
    unsigned short* Qbase = QHd + head * D_;
    const unsigned short* Kbase = Kh + head * D_;
    const unsigned short* Vbase = Vt + head * D_;   // [d][s] per head

    for (int i = t; i < S_; i += 256)
        mskf[i] = (mask[b * S_ + i] == 0) ? -1e9f : 0.f;

    bf16x8 qf[4];
    #pragma unroll
    for (int ks = 0; ks < 4; ++ks)
        qf[ks] = *(const bf16x8*)(
            Qbase + (size_t)(q0 + qg * 32 + l31) * D_ + ks * 16 + hi * 8);

    bf16x8 onesA;
    #pragma unroll
    for (int i = 0; i < 8; ++i) onesA[i] = (short)0x3F80;

    f32x16 O0, O1, O2;
    #pragma unroll
    for (int i = 0; i < 16; ++i) { O0[i] = 0.f; O1[i] = 0.f; O2[i] = 0.f; }
    const float SC2 = 0.125f * 1.44269504089f;      // 1/sqrt(D) * log2(e)

    #define STAGE(kt_) do {                                                        \
        const int bf_ = (kt_) & 1, k0_ = (kt_) * 64;                               \
        _Pragma("unroll")                                                          \
        for (int i_ = 0; i_ < 2; ++i_) {                                           \
            const int c_ = w * 2 + i_;                                             \
            const int u_ = c_ * 64 + lane;                                         \
            const int row_ = u_ >> 3;                                              \
            const int sc_ = ((u_ & 7) ^ (row_ & 7)) << 3;                          \
            gl_lds16(Kbase + (size_t)(k0_ + row_) * D_ + sc_,                      \
                     KsL + bf_ * 4096 + c_ * 512);                                 \
            gl_lds16(Vbase + (size_t)row_ * S_ + k0_ + sc_,                        \
                     VsL + bf_ * 4096 + c_ * 512);                                 \
        }                                                                          \
    } while (0)

    STAGE(0);
    __syncthreads();

    for (int kt = 0; kt < S_ / 64; ++kt) {
        const int bf = kt & 1;
        const int k0 = kt * 64;
        if (kt + 1 < S_ / 64) STAGE(kt + 1);

        // ---- QK^T for own key-half: A = K rows (kh*32..+31), B = Q ----
        f32x16 acc;
        #pragma unroll
        for (int i = 0; i < 16; ++i) acc[i] = 0.f;
        const int krow = kh * 32 + l31;
        const unsigned short* Kb = KsL + bf * 4096 + krow * 64;
        const int rwk = krow & 7;
        __builtin_amdgcn_s_setprio(1);
        #pragma unroll
        for (int ks = 0; ks < 4; ++ks) {
            const bf16x8 kf = *(const bf16x8*)&Kb[(((ks * 2 + hi) ^ rwk) << 3)];
            acc = MFMA32(kf, qf[ks], acc);
        }
        __builtin_amdgcn_s_setprio(0);
        // ---- mask + exp2 (key = kh*32 + r4 + 8b + 4hi + k0) ----
        float p[16];
        #pragma unroll
        for (int bq = 0; bq < 4; ++bq) {
            const float4 ms4 = *(const float4*)&mskf[k0 + kh * 32 + bq * 8 + hi * 4];
            p[4 * bq + 0] = __builtin_amdgcn_exp2f(fmaf(acc[4 * bq + 0], SC2, ms4.x));
            p[4 * bq + 1] = __builtin_amdgcn_exp2f(fmaf(acc[4 * bq + 1], SC2, ms4.y));
            p[4 * bq + 2] = __builtin_amdgcn_exp2f(fmaf(acc[4 * bq + 2], SC2, ms4.z));
            p[4 * bq + 3] = __builtin_amdgcn_exp2f(fmaf(acc[4 * bq + 3], SC2, ms4.w));
        }
        // ---- pack pairs ----
        unsigned pkv[8];
        #pragma unroll
        for (int bq = 0; bq < 4; ++bq) {
            pkv[2 * bq + 0] = pk2(p[4 * bq + 0], p[4 * bq + 1]);
            pkv[2 * bq + 1] = pk2(p[4 * bq + 2], p[4 * bq + 3]);
        }
        // ---- cross-half swap -> PV B-frags (keys [kh*32+ksl*16, +16)) ----
        bf16x8 pfrag[2];
        #pragma unroll
        for (int ksl = 0; ksl < 2; ++ksl) {
            unsigned m0 = pkv[4 * ksl + 0], m2 = pkv[4 * ksl + 2];
            asm volatile("v_permlane32_swap_b32 %0, %1" : "+v"(m0), "+v"(m2));
            unsigned m1 = pkv[4 * ksl + 1], m3 = pkv[4 * ksl + 3];
            asm volatile("v_permlane32_swap_b32 %0, %1" : "+v"(m1), "+v"(m3));
            union { unsigned u[4]; bf16x8 v; } pu;
            pu.u[0] = m0; pu.u[1] = m1; pu.u[2] = m2; pu.u[3] = m3;
            pfrag[ksl] = pu.v;
        }
        // ---- PV: O^T += mfma32(V rows, P); + lsum via ones-MFMA ----
        __builtin_amdgcn_s_setprio(1);
        #pragma unroll
        for (int dblk = 0; dblk < 2; ++dblk) {
            const int vrow = dblk * 32 + l31;
            const unsigned short* Vb = VsL + bf * 4096 + vrow * 64;
            const int rwv = vrow & 7;
            #pragma unroll
            for (int ksl = 0; ksl < 2; ++ksl) {
                const bf16x8 vf =
                    *(const bf16x8*)&Vb[(((kh * 4 + ksl * 2 + hi) ^ rwv) << 3)];
                if (dblk == 0) O0 = MFMA32(vf, pfrag[ksl], O0);
                else           O1 = MFMA32(vf, pfrag[ksl], O1);
            }
        }
        O2 = MFMA32(onesA, pfrag[0], O2);
        O2 = MFMA32(onesA, pfrag[1], O2);
        __builtin_amdgcn_s_setprio(0);
        __syncthreads();                        // single barrier per tile
    }
    #undef STAGE

    float lsum = O2[0];

    // ---- cross-wave (key-half) reduction through dead K/V LDS ----
    if (kh == 1) {
        float* R = qg ? (float*)VsL : (float*)KsL;
        #pragma unroll
        for (int i = 0; i < 16; ++i) R[lane * 33 + i]      = O0[i];
        #pragma unroll
        for (int i = 0; i < 16; ++i) R[lane * 33 + 16 + i] = O1[i];
        if (hi == 0) R[2112 + l31] = lsum;
    }
    __syncthreads();
    if (kh == 0) {
        const float* R = qg ? (const float*)VsL : (const float*)KsL;
        #pragma unroll
        for (int i = 0; i < 16; ++i) O0[i] += R[lane * 33 + i];
        #pragma unroll
        for (int i = 0; i < 16; ++i) O1[i] += R[lane * 33 + 16 + i];
        lsum += R[2112 + l31];
        const float inv = 1.f / lsum;

        unsigned short* Orow = Qbase + (size_t)(q0 + qg * 32 + l31) * D_;
        #pragma unroll
        for (int dblk = 0; dblk < 2; ++dblk) {
            #pragma unroll
            for (int bq = 0; bq < 4; ++bq) {
                const float v0 = (dblk ? O1[4 * bq + 0] : O0[4 * bq + 0]) * inv;
                const float v1 = (dblk ? O1[4 * bq + 1] : O0[4 * bq + 1]) * inv;
                const float v2 = (dblk ? O1[4 * bq + 2] : O0[4 * bq + 2]) * inv;
                const float v3 = (dblk ? O1[4 * bq + 3] : O0[4 * bq + 3]) * inv;
                uint2 st; st.x = pk2(v0, v1); st.y = pk2(v2, v3);
                *(uint2*)&Orow[dblk * 32 + bq * 8 + hi * 4] = st;
            }
        }
    }
}

// ---------------------------------------------------------------------------
// MFMA output GEMM v4: 64x64 tiles for 2x TLP (1024 blocks = 4/CU = 16
// waves/CU, was 512 = 2/CU = 8 waves). Both tiles gload_lds, double-buffered,
// one barrier per K-step. LDS 32KB.
// ---------------------------------------------------------------------------
__global__ __launch_bounds__(256, 4) void out_mfma(
    const unsigned short* __restrict__ Hd, const unsigned short* __restrict__ Wot,
    const float* __restrict__ bias, float* __restrict__ Out)
{
    __shared__ __align__(16) unsigned short As2[2][4096];   // [64][64] swz
    __shared__ __align__(16) unsigned short Bs2[2][4096];   // [64][64] swz
    const int t = threadIdx.x;
    const int w = t >> 6, lane = t & 63;
    const int quad = lane >> 4, l15 = lane & 15;
    const int wr = w >> 1, wc = w & 1;
    const int m0 = blockIdx.x * 64, n0 = blockIdx.y * 64;
    const int bb = m0 >> 11, s0 = m0 & (S_ - 1);

    const f32x4 zero = {0.f, 0.f, 0.f, 0.f};
    f32x4 acc[2][2];
    #pragma unroll
    for (int i = 0; i < 2; ++i)
        #pragma unroll
        for (int j = 0; j < 2; ++j) acc[i][j] = zero;

    #define OSTAGE(s_, bfx_) do {                                              \
        const int hk_ = (s_);                                                  \
        const unsigned short* Ab_ = Hd + (((size_t)bb * NH_ + hk_) * S_ + s0)  \
                                    * D_;                                      \
        _Pragma("unroll")                                                      \
        for (int i_ = 0; i_ < 2; ++i_) {                                       \
            const int c_ = w * 2 + i_, u_ = c_ * 64 + lane, row_ = u_ >> 3;    \
            const int sc_ = ((u_ & 7) ^ (row_ & 7)) << 3;                      \
            gl_lds16(Ab_ + (size_t)row_ * D_ + sc_, As2[bfx_] + c_ * 512);     \
            gl_lds16(Wot + (size_t)(n0 + row_) * H_ + hk_ * 64 + sc_,          \
                     Bs2[bfx_] + c_ * 512);                                    \
        }                                                                      \
    } while (0)

    OSTAGE(0, 0);
    __syncthreads();

    for (int s = 0; s < 8; ++s) {
        const int cur = s & 1;
        if (s + 1 < 8) OSTAGE(s + 1, cur ^ 1);
        #pragma unroll
        for (int ks = 0; ks < 2; ++ks) {
            bf16x8 af[2], bfr[2];
            #pragma unroll
            for (int i = 0; i < 2; ++i) {
                const int row = wr * 32 + i * 16 + l15;
                af[i] = *(const bf16x8*)&As2[cur][row * 64 +
                            (((ks * 4 + quad) ^ (row & 7)) << 3)];
            }
            #pragma unroll
            for (int j = 0; j < 2; ++j) {
                const int nrw = wc * 32 + j * 16 + l15;
                bfr[j] = *(const bf16x8*)&Bs2[cur][nrw * 64 +
                            (((ks * 4 + quad) ^ (nrw & 7)) << 3)];
            }
            #pragma unroll
            for (int i = 0; i < 2; ++i)
                #pragma unroll
                for (int j = 0; j < 2; ++j)
                    acc[i][j] = MFMA16(af[i], bfr[j], acc[i][j]);
        }
        __syncthreads();    // drains next-tile gload_lds; one barrier per step
    }
    #undef OSTAGE

    #pragma unroll
    for (int i = 0; i < 2; ++i)
        #pragma unroll
        for (int r = 0; r < 4; ++r) {
            const int m = m0 + wr * 32 + i * 16 + quad * 4 + r;
            #pragma unroll
            for (int j = 0; j < 2; ++j) {
                const int n = n0 + wc * 32 + j * 16 + l15;
                Out[(size_t)m * H_ + n] = acc[i][j][r] + bias[n];
            }
        }
}

// ---------------------------------------------------------------------------
__global__ void fill_kernel(float* __restrict__ out, float val, int n) {
    const int i = blockIdx.x * 256 + threadIdx.x;
    if (i < n) out[i] = val;
}

// ---------------------------------------------------------------------------
extern "C" void kernel_launch(void* const* d_in, const int* in_sizes, int n_in,
                              void* d_out, int out_size, void* d_ws, size_t ws_size,
                              hipStream_t stream) {
    const float* q   = (const float*)d_in[0];
    const float* k   = (const float*)d_in[1];
    const float* v   = (const float*)d_in[2];
    const float* k_b = (const float*)d_in[3];
    const int*   msk = (const int*)d_in[4];
    const float* Wq  = (const float*)d_in[5];
    const float* bq  = (const float*)d_in[6];
    const float* Wk  = (const float*)d_in[7];
    const float* bk  = (const float*)d_in[8];
    const float* Wv  = (const float*)d_in[9];
    const float* bv  = (const float*)d_in[10];
    const float* Wkb = (const float*)d_in[11];
    const float* bkb = (const float*)d_in[12];
    const float* Wo  = (const float*)d_in[13];
    const float* bo  = (const float*)d_in[14];
    float* out = (float*)d_out;

    const size_t PER  = (size_t)B_ * NH_ * S_ * D_;
    const size_t NEED = 3 * PER * sizeof(unsigned short);   // 24 MiB (proven)
    if (ws_size < NEED) {   // tripwire (dead path)
        fill_kernel<<<(out_size + 255) / 256, 256, 0, stream>>>(
            out, (float)((ws_size >> 20) + 2), out_size);
        return;
    }
    unsigned short* wsh = (unsigned short*)d_ws;
    unsigned short* Qf  = wsh;              // Q head-major; becomes Hd after attn
    unsigned short* Kf  = wsh + PER;        // K' head-major; Wo_t scratch after attn
    unsigned short* Vf  = wsh + 2 * PER;    // V transposed [b,h,d,s]

    // d_out doubles as scratch for the 4 projection weights until out_mfma.
    unsigned short* Wt = (unsigned short*)d_out;

    dim3 gw(8, 8, 4);
    prep_w<<<gw, 256, 0, stream>>>(Wq, Wk, Wkb, Wv, Wt);

    dim3 gp((B_ * S_) / 128, H_ / 128, 4);  // 64 x 4 x 4 = 1024 balanced blocks
    proj_all<<<gp, 256, 0, stream>>>(q, k, v, k_b, Wt, bq, bk, bkb, bv, Qf, Kf, Vf);

    dim3 ga(S_ / 64, NH_, B_);              // 32 x 8 x 4 = 1024 blocks
    attn_mfma<<<ga, 256, 0, stream>>>(Qf, Kf, Vf, msk);

    // Kf is dead after attn: reuse it for transposed Wo.
    dim3 gw1(8, 8, 1);
    prep_w<<<gw1, 256, 0, stream>>>(Wo, Wo, Wo, Wo, Kf);

    dim3 go((B_ * S_) / 64, H_ / 64, 1);    // 128 x 8 = 1024 blocks
    out_mfma<<<go, 256, 0, stream>>>(Qf, Kf, bo, out);
}

// Round 8
// 255.698 us; speedup vs baseline: 1.2929x; 1.2929x over previous
//
#include <hip/hip_runtime.h>
#include <hip/hip_bf16.h>
#include <math.h>

#define B_  4
#define S_  2048
#define H_  512
#define NH_ 8
#define D_  64

typedef __attribute__((ext_vector_type(8))) short bf16x8;   // 8 bf16 = 4 VGPR
typedef __attribute__((ext_vector_type(4))) float f32x4;
typedef __attribute__((ext_vector_type(16))) float f32x16;
#define MFMA16(a, b, c) __builtin_amdgcn_mfma_f32_16x16x32_bf16(a, b, c, 0, 0, 0)
#define MFMA32(a, b, c) __builtin_amdgcn_mfma_f32_32x32x16_bf16(a, b, c, 0, 0, 0)

__device__ __forceinline__ unsigned short f2bf(float f) {
    union { float f; unsigned int i; } x; x.f = f;
    unsigned int i = x.i;
    i += 0x7fffu + ((i >> 16) & 1u);
    return (unsigned short)(i >> 16);
}
// packed fp32 pair -> bf16 pair (RNE), lo in low 16 bits
__device__ __forceinline__ unsigned int pk2(float lo, float hi) {
    union { __hip_bfloat162 h; unsigned int u; } c;
    c.h = __float22bfloat162_rn(make_float2(lo, hi));
    return c.u;
}
// async global->LDS, 16 B per lane; lds ptr must be wave-uniform
__device__ __forceinline__ void gl_lds16(const void* g, void* l) {
    __builtin_amdgcn_global_load_lds(
        (const __attribute__((address_space(1))) unsigned int*)g,
        (__attribute__((address_space(3))) unsigned int*)l, 16, 0, 0);
}

// ---------------------------------------------------------------------------
// Weight prep: transpose+convert 512x512 fp32 W -> bf16 Wt[n][k] (n-major).
// ---------------------------------------------------------------------------
__global__ __launch_bounds__(256) void prep_w(
    const float* __restrict__ W0, const float* __restrict__ W1,
    const float* __restrict__ W2, const float* __restrict__ W3,
    unsigned short* __restrict__ Wt)
{
    const float* Ws[4] = {W0, W1, W2, W3};
    const float* W = Ws[blockIdx.z];
    unsigned short* Y = Wt + (size_t)blockIdx.z * H_ * H_;
    __shared__ float Tl[64][68];
    const int t = threadIdx.x;
    const int k0 = blockIdx.y * 64, n0 = blockIdx.x * 64;
    #pragma unroll
    for (int i = 0; i < 4; ++i) {
        const int e = (t + 256 * i) * 4;
        const int r = e >> 6, c = e & 63;
        const float4 a = *(const float4*)(W + (size_t)(k0 + r) * H_ + n0 + c);
        Tl[c + 0][r] = a.x; Tl[c + 1][r] = a.y;
        Tl[c + 2][r] = a.z; Tl[c + 3][r] = a.w;
    }
    __syncthreads();
    #pragma unroll
    for (int i = 0; i < 4; ++i) {
        const int e = (t + 256 * i) * 4;
        const int n = e >> 6, c = e & 63;
        uint2 p;
        p.x = pk2(Tl[n][c + 0], Tl[n][c + 1]);
        p.y = pk2(Tl[n][c + 2], Tl[n][c + 3]);
        *(uint2*)(Y + (size_t)(n0 + n) * H_ + k0 + c) = p;
    }
}

// ---------------------------------------------------------------------------
// K projection (dual GEMM): K' = k@Wk + k_b@Wkb + (bk+bkb), head-major out.
// 64-row x 128-col tile, 16 K-steps (pass-major: all Wk then all Wkb --
// accumulation order bitwise-identical to the R6 z=1 path). All loops have
// COMPILE-TIME bounds (R7's runtime-guarded unrolls caused scratch spill:
// WRITE_SIZE 24->216MB). Grid (64,4,2) = 512 blocks; LDS 24KB.
// Co-scheduled with proj_qv for balanced CU load.
// ---------------------------------------------------------------------------
__global__ __launch_bounds__(256, 4) void proj_k(
    const float* __restrict__ k, const float* __restrict__ k_b,
    const unsigned short* __restrict__ Wt,
    const float* __restrict__ bk, const float* __restrict__ bkb,
    unsigned short* __restrict__ Kf)
{
    __shared__ __align__(16) unsigned short As[4096];   // [64][64] swz
    __shared__ __align__(16) unsigned short Bs[8192];   // [128][64] swz
    const size_t WSZ = (size_t)H_ * H_;
    const int t = threadIdx.x;
    const int w = t >> 6, lane = t & 63;
    const int quad = lane >> 4, l15 = lane & 15;
    const int wr = w >> 1, wc = w & 1;
    const int m0 = blockIdx.x * 128 + blockIdx.z * 64;
    const int n0 = blockIdx.y * 128;

    const f32x4 zero = {0.f, 0.f, 0.f, 0.f};
    f32x4 acc[2][4];
    #pragma unroll
    for (int i = 0; i < 2; ++i)
        #pragma unroll
        for (int j = 0; j < 4; ++j) acc[i][j] = zero;

    for (int p = 0; p < 2; ++p) {
        const float* Xp = p ? k_b : k;
        const unsigned short* Wp = Wt + (p ? 2 : 1) * WSZ;
        for (int kb0 = 0; kb0 < H_; kb0 += 64) {
            __syncthreads();
            // B tile 128n x 64k: async gload_lds, pre-swizzled source
            #pragma unroll
            for (int i = 0; i < 4; ++i) {
                const int c = w * 4 + i;
                const int u = c * 64 + lane;
                const int row = u >> 3;
                const int sc = ((u & 7) ^ (row & 7)) << 3;
                gl_lds16(Wp + (size_t)(n0 + row) * H_ + kb0 + sc, Bs + c * 512);
            }
            // A tile 64m x 64k fp32 -> bf16, swizzled write (4 float4/thread)
            float4 av[4];
            #pragma unroll
            for (int i = 0; i < 4; ++i) {
                const int e = (t + 256 * i) * 4;
                av[i] = *(const float4*)(Xp + (size_t)(m0 + (e >> 6)) * H_ + kb0 + (e & 63));
            }
            #pragma unroll
            for (int i = 0; i < 4; ++i) {
                const int e = (t + 256 * i) * 4;
                const int row = e >> 6, kc = e & 63;
                uint2 pr; pr.x = pk2(av[i].x, av[i].y); pr.y = pk2(av[i].z, av[i].w);
                *(uint2*)&As[row * 64 + ((((kc >> 3) ^ (row & 7)) << 3) | (kc & 7))] = pr;
            }
            __syncthreads();
            #pragma unroll
            for (int ks = 0; ks < 2; ++ks) {
                bf16x8 af[2], bfr[4];
                #pragma unroll
                for (int i = 0; i < 2; ++i) {
                    const int row = wr * 32 + i * 16 + l15;
                    af[i] = *(const bf16x8*)&As[row * 64 +
                                (((ks * 4 + quad) ^ (row & 7)) << 3)];
                }
                #pragma unroll
                for (int j = 0; j < 4; ++j) {
                    const int nrw = wc * 64 + j * 16 + l15;
                    bfr[j] = *(const bf16x8*)&Bs[nrw * 64 +
                                (((ks * 4 + quad) ^ (nrw & 7)) << 3)];
                }
                #pragma unroll
                for (int i = 0; i < 2; ++i)
                    #pragma unroll
                    for (int j = 0; j < 4; ++j)
                        acc[i][j] = MFMA16(af[i], bfr[j], acc[i][j]);
            }
        }
    }

    const int bb = m0 >> 11, s0 = m0 & (S_ - 1);
    #pragma unroll
    for (int i = 0; i < 2; ++i)
        #pragma unroll
        for (int r = 0; r < 4; ++r) {
            const int s = s0 + wr * 32 + i * 16 + quad * 4 + r;
            #pragma unroll
            for (int j = 0; j < 4; ++j) {
                const int nn = n0 + wc * 64 + j * 16 + l15;
                const int h = nn >> 6, d = nn & 63;
                const float val = acc[i][j][r] + bk[nn] + bkb[nn];
                Kf[(((size_t)bb * NH_ + h) * S_ + s) * D_ + d] = f2bf(val);
            }
        }
}

// ---------------------------------------------------------------------------
// Q / V projections: z=0 Q (head-major out), z=1 V (transposed epilogue ->
// Vt[b,h,d,s]). Exact R6 structure: 128x128 tile, 8 K-steps, 2x2 wave
// quadrants. Grid (64,4,2) = 512 blocks; LDS 34.8KB.
// ---------------------------------------------------------------------------
__global__ __launch_bounds__(256, 4) void proj_qv(
    const float* __restrict__ q,  const float* __restrict__ v,
    const unsigned short* __restrict__ Wt,
    const float* __restrict__ bq, const float* __restrict__ bv,
    unsigned short* __restrict__ Qf, unsigned short* __restrict__ Vf)
{
    __shared__ __align__(16) unsigned short LB[17408];
    unsigned short* As = LB;            // 8192 halfs
    unsigned short* Bs = LB + 8192;     // 8192 halfs

    const int z = blockIdx.z;           // 0 = Q, 1 = V(transposed)
    const size_t WSZ = (size_t)H_ * H_;
    const float* X = z ? v : q;
    const unsigned short* Wp = z ? Wt + 3 * WSZ : Wt;
    const float* bias = z ? bv : bq;
    unsigned short* Y = z ? Vf : Qf;

    const int t = threadIdx.x;
    const int w = t >> 6, lane = t & 63;
    const int quad = lane >> 4, l15 = lane & 15;
    const int wr = w >> 1, wc = w & 1;
    const int m0 = blockIdx.x * 128, n0 = blockIdx.y * 128;

    const f32x4 zero = {0.f, 0.f, 0.f, 0.f};
    f32x4 acc[4][4];
    #pragma unroll
    for (int i = 0; i < 4; ++i)
        #pragma unroll
        for (int j = 0; j < 4; ++j) acc[i][j] = zero;

    for (int kb0 = 0; kb0 < H_; kb0 += 64) {
        __syncthreads();
        #pragma unroll
        for (int i = 0; i < 4; ++i) {
            const int c = w * 4 + i;
            const int u = c * 64 + lane;
            const int row = u >> 3;
            const int sc  = ((u & 7) ^ (row & 7)) << 3;
            gl_lds16(Wp + (size_t)(n0 + row) * H_ + kb0 + sc, Bs + c * 512);
        }
        float4 av[8];
        #pragma unroll
        for (int i = 0; i < 8; ++i) {
            const int e = (t + 256 * i) * 4;
            av[i] = *(const float4*)(X + (size_t)(m0 + (e >> 6)) * H_ + kb0 + (e & 63));
        }
        #pragma unroll
        for (int i = 0; i < 8; ++i) {
            const int e = (t + 256 * i) * 4;
            const int row = e >> 6, kc = e & 63;
            uint2 p; p.x = pk2(av[i].x, av[i].y); p.y = pk2(av[i].z, av[i].w);
            *(uint2*)&As[row * 64 + ((((kc >> 3) ^ (row & 7)) << 3) | (kc & 7))] = p;
        }
        __syncthreads();
        #pragma unroll
        for (int ks = 0; ks < 2; ++ks) {
            bf16x8 af[4], bfr[4];
            #pragma unroll
            for (int i = 0; i < 4; ++i) {
                const int row = wr * 64 + i * 16 + l15;
                af[i] = *(const bf16x8*)&As[row * 64 +
                            (((ks * 4 + quad) ^ (row & 7)) << 3)];
            }
            #pragma unroll
            for (int j = 0; j < 4; ++j) {
                const int nrw = wc * 64 + j * 16 + l15;
                bfr[j] = *(const bf16x8*)&Bs[nrw * 64 +
                            (((ks * 4 + quad) ^ (nrw & 7)) << 3)];
            }
            #pragma unroll
            for (int i = 0; i < 4; ++i)
                #pragma unroll
                for (int j = 0; j < 4; ++j)
                    acc[i][j] = MFMA16(af[i], bfr[j], acc[i][j]);
        }
    }

    const int bb = m0 >> 11, s0 = m0 & (S_ - 1);
    if (z == 0) {
        #pragma unroll
        for (int i = 0; i < 4; ++i)
            #pragma unroll
            for (int r = 0; r < 4; ++r) {
                const int s = s0 + wr * 64 + i * 16 + quad * 4 + r;
                #pragma unroll
                for (int j = 0; j < 4; ++j) {
                    const int nn = n0 + wc * 64 + j * 16 + l15;
                    const int h = nn >> 6, d = nn & 63;
                    Y[(((size_t)bb * NH_ + h) * S_ + s) * D_ + d] =
                        f2bf(acc[i][j][r] + bias[nn]);
                }
            }
    } else {
        __syncthreads();
        #pragma unroll
        for (int i = 0; i < 4; ++i)
            #pragma unroll
            for (int r = 0; r < 4; ++r) {
                const int ml = wr * 64 + i * 16 + quad * 4 + r;
                #pragma unroll
                for (int j = 0; j < 4; ++j) {
                    const int nl = wc * 64 + j * 16 + l15;
                    LB[nl * 136 + ml] = f2bf(acc[i][j][r] + bias[n0 + nl]);
                }
            }
        __syncthreads();
        const int nr = t >> 1, half = t & 1;
        const int nn = n0 + nr, h = nn >> 6, d = nn & 63;
        const size_t vbase = (((size_t)bb * NH_ + h) * D_ + d) * S_ + s0 + half * 64;
        #pragma unroll
        for (int i = 0; i < 16; ++i)
            *(ushort4*)(Y + vbase + i * 4) =
                *(const ushort4*)&LB[nr * 136 + half * 64 + i * 4];
    }
}

// ---------------------------------------------------------------------------
// MFMA flash attention v5 (unchanged control): key-split waves + lsum on the
// MFMA pipe via ones-MFMA.
// ---------------------------------------------------------------------------
__global__ __launch_bounds__(256, 4) void attn_mfma(
    unsigned short* QHd,
    const unsigned short* __restrict__ Kh, const unsigned short* __restrict__ Vt,
    const int* __restrict__ mask)
{
    const int b = blockIdx.z, h = blockIdx.y;
    const int q0 = blockIdx.x * 64;
    const int t = threadIdx.x;
    const int w = t >> 6, lane = t & 63;
    const int hi = lane >> 5, l31 = lane & 31;
    const int qg = w & 1, kh = w >> 1;

    __shared__ __align__(16) unsigned short KsL[2 * 4096];  // [2][64 key][64 d] swz
    __shared__ __align__(16) unsigned short VsL[2 * 4096];  // [2][64 d][64 key] swz
    __shared__ float mskf[S_];                              // -1e9 / 0 per key

    const size_t head = ((size_t)b * NH_ + h) * S_;
    unsigned short* Qbase = QHd + head * D_;
    const unsigned short* Kbase = Kh + head * D_;
    const unsigned short* Vbase = Vt + head * D_;   // [d][s] per head

    for (int i = t; i < S_; i += 256)
        mskf[i] = (mask[b * S_ + i] == 0) ? -1e9f : 0.f;

    bf16x8 qf[4];
    #pragma unroll
    for (int ks = 0; ks < 4; ++ks)
        qf[ks] = *(const bf16x8*)(
            Qbase + (size_t)(q0 + qg * 32 + l31) * D_ + ks * 16 + hi * 8);

    bf16x8 onesA;
    #pragma unroll
    for (int i = 0; i < 8; ++i) onesA[i] = (short)0x3F80;

    f32x16 O0, O1, O2;
    #pragma unroll
    for (int i = 0; i < 16; ++i) { O0[i] = 0.f; O1[i] = 0.f; O2[i] = 0.f; }
    const float SC2 = 0.125f * 1.44269504089f;      // 1/sqrt(D) * log2(e)

    #define STAGE(kt_) do {                                                        \
        const int bf_ = (kt_) & 1, k0_ = (kt_) * 64;                               \
        _Pragma("unroll")                                                          \
        for (int i_ = 0; i_ < 2; ++i_) {                                           \
            const int c_ = w * 2 + i_;                                             \
            const int u_ = c_ * 64 + lane;                                         \
            const int row_ = u_ >> 3;                                              \
            const int sc_ = ((u_ & 7) ^ (row_ & 7)) << 3;                          \
            gl_lds16(Kbase + (size_t)(k0_ + row_) * D_ + sc_,                      \
                     KsL + bf_ * 4096 + c_ * 512);                                 \
            gl_lds16(Vbase + (size_t)row_ * S_ + k0_ + sc_,                        \
                     VsL + bf_ * 4096 + c_ * 512);                                 \
        }                                                                          \
    } while (0)

    STAGE(0);
    __syncthreads();

    for (int kt = 0; kt < S_ / 64; ++kt) {
        const int bf = kt & 1;
        const int k0 = kt * 64;
        if (kt + 1 < S_ / 64) STAGE(kt + 1);

        f32x16 acc;
        #pragma unroll
        for (int i = 0; i < 16; ++i) acc[i] = 0.f;
        const int krow = kh * 32 + l31;
        const unsigned short* Kb = KsL + bf * 4096 + krow * 64;
        const int rwk = krow & 7;
        __builtin_amdgcn_s_setprio(1);
        #pragma unroll
        for (int ks = 0; ks < 4; ++ks) {
            const bf16x8 kf = *(const bf16x8*)&Kb[(((ks * 2 + hi) ^ rwk) << 3)];
            acc = MFMA32(kf, qf[ks], acc);
        }
        __builtin_amdgcn_s_setprio(0);
        float p[16];
        #pragma unroll
        for (int bq = 0; bq < 4; ++bq) {
            const float4 ms4 = *(const float4*)&mskf[k0 + kh * 32 + bq * 8 + hi * 4];
            p[4 * bq + 0] = __builtin_amdgcn_exp2f(fmaf(acc[4 * bq + 0], SC2, ms4.x));
            p[4 * bq + 1] = __builtin_amdgcn_exp2f(fmaf(acc[4 * bq + 1], SC2, ms4.y));
            p[4 * bq + 2] = __builtin_amdgcn_exp2f(fmaf(acc[4 * bq + 2], SC2, ms4.z));
            p[4 * bq + 3] = __builtin_amdgcn_exp2f(fmaf(acc[4 * bq + 3], SC2, ms4.w));
        }
        unsigned pkv[8];
        #pragma unroll
        for (int bq = 0; bq < 4; ++bq) {
            pkv[2 * bq + 0] = pk2(p[4 * bq + 0], p[4 * bq + 1]);
            pkv[2 * bq + 1] = pk2(p[4 * bq + 2], p[4 * bq + 3]);
        }
        bf16x8 pfrag[2];
        #pragma unroll
        for (int ksl = 0; ksl < 2; ++ksl) {
            unsigned m0 = pkv[4 * ksl + 0], m2 = pkv[4 * ksl + 2];
            asm volatile("v_permlane32_swap_b32 %0, %1" : "+v"(m0), "+v"(m2));
            unsigned m1 = pkv[4 * ksl + 1], m3 = pkv[4 * ksl + 3];
            asm volatile("v_permlane32_swap_b32 %0, %1" : "+v"(m1), "+v"(m3));
            union { unsigned u[4]; bf16x8 v; } pu;
            pu.u[0] = m0; pu.u[1] = m1; pu.u[2] = m2; pu.u[3] = m3;
            pfrag[ksl] = pu.v;
        }
        __builtin_amdgcn_s_setprio(1);
        #pragma unroll
        for (int dblk = 0; dblk < 2; ++dblk) {
            const int vrow = dblk * 32 + l31;
            const unsigned short* Vb = VsL + bf * 4096 + vrow * 64;
            const int rwv = vrow & 7;
            #pragma unroll
            for (int ksl = 0; ksl < 2; ++ksl) {
                const bf16x8 vf =
                    *(const bf16x8*)&Vb[(((kh * 4 + ksl * 2 + hi) ^ rwv) << 3)];
                if (dblk == 0) O0 = MFMA32(vf, pfrag[ksl], O0);
                else           O1 = MFMA32(vf, pfrag[ksl], O1);
            }
        }
        O2 = MFMA32(onesA, pfrag[0], O2);
        O2 = MFMA32(onesA, pfrag[1], O2);
        __builtin_amdgcn_s_setprio(0);
        __syncthreads();                        // single barrier per tile
    }
    #undef STAGE

    float lsum = O2[0];

    if (kh == 1) {
        float* R = qg ? (float*)VsL : (float*)KsL;
        #pragma unroll
        for (int i = 0; i < 16; ++i) R[lane * 33 + i]      = O0[i];
        #pragma unroll
        for (int i = 0; i < 16; ++i) R[lane * 33 + 16 + i] = O1[i];
        if (hi == 0) R[2112 + l31] = lsum;
    }
    __syncthreads();
    if (kh == 0) {
        const float* R = qg ? (const float*)VsL : (const float*)KsL;
        #pragma unroll
        for (int i = 0; i < 16; ++i) O0[i] += R[lane * 33 + i];
        #pragma unroll
        for (int i = 0; i < 16; ++i) O1[i] += R[lane * 33 + 16 + i];
        lsum += R[2112 + l31];
        const float inv = 1.f / lsum;

        unsigned short* Orow = Qbase + (size_t)(q0 + qg * 32 + l31) * D_;
        #pragma unroll
        for (int dblk = 0; dblk < 2; ++dblk) {
            #pragma unroll
            for (int bq = 0; bq < 4; ++bq) {
                const float v0 = (dblk ? O1[4 * bq + 0] : O0[4 * bq + 0]) * inv;
                const float v1 = (dblk ? O1[4 * bq + 1] : O0[4 * bq + 1]) * inv;
                const float v2 = (dblk ? O1[4 * bq + 2] : O0[4 * bq + 2]) * inv;
                const float v3 = (dblk ? O1[4 * bq + 3] : O0[4 * bq + 3]) * inv;
                uint2 st; st.x = pk2(v0, v1); st.y = pk2(v2, v3);
                *(uint2*)&Orow[dblk * 32 + bq * 8 + hi * 4] = st;
            }
        }
    }
}

// ---------------------------------------------------------------------------
// MFMA output GEMM (R5/R6-proven dbuf): Out_f32[m,n] = Hd@Wo + bo.
// Both tiles gload_lds; double-buffered, ONE barrier per K-step. 128x64
// tiles, grid (64,8) = 512 blocks (grid-limited 2/CU -> 48KB LDS is free).
// ---------------------------------------------------------------------------
__global__ __launch_bounds__(256) void out_mfma(
    const unsigned short* __restrict__ Hd, const unsigned short* __restrict__ Wot,
    const float* __restrict__ bias, float* __restrict__ Out)
{
    __shared__ __align__(16) unsigned short As2[2][8192];   // [128][64] swz
    __shared__ __align__(16) unsigned short Bs2[2][4096];   // [64][64] swz
    const int t = threadIdx.x;
    const int w = t >> 6, lane = t & 63;
    const int quad = lane >> 4, l15 = lane & 15;
    const int wr = w >> 1, wc = w & 1;
    const int m0 = blockIdx.x * 128, n0 = blockIdx.y * 64;
    const int bb = m0 >> 11, s0 = m0 & (S_ - 1);

    const f32x4 zero = {0.f, 0.f, 0.f, 0.f};
    f32x4 acc[4][2];
    #pragma unroll
    for (int i = 0; i < 4; ++i)
        #pragma unroll
        for (int j = 0; j < 2; ++j) acc[i][j] = zero;

    #define OSTAGE(s_, bfx_) do {                                              \
        const int hk_ = (s_);                                                  \
        const unsigned short* Ab_ = Hd + (((size_t)bb * NH_ + hk_) * S_ + s0)  \
                                    * D_;                                      \
        _Pragma("unroll")                                                      \
        for (int i_ = 0; i_ < 4; ++i_) {                                       \
            const int c_ = w * 4 + i_, u_ = c_ * 64 + lane, row_ = u_ >> 3;    \
            const int sc_ = ((u_ & 7) ^ (row_ & 7)) << 3;                      \
            gl_lds16(Ab_ + (size_t)row_ * D_ + sc_, As2[bfx_] + c_ * 512);     \
        }                                                                      \
        _Pragma("unroll")                                                      \
        for (int i_ = 0; i_ < 2; ++i_) {                                       \
            const int c_ = w * 2 + i_, u_ = c_ * 64 + lane, row_ = u_ >> 3;    \
            const int sc_ = ((u_ & 7) ^ (row_ & 7)) << 3;                      \
            gl_lds16(Wot + (size_t)(n0 + row_) * H_ + hk_ * 64 + sc_,          \
                     Bs2[bfx_] + c_ * 512);                                    \
        }                                                                      \
    } while (0)

    OSTAGE(0, 0);
    __syncthreads();

    for (int s = 0; s < 8; ++s) {
        const int cur = s & 1;
        if (s + 1 < 8) OSTAGE(s + 1, cur ^ 1);
        #pragma unroll
        for (int ks = 0; ks < 2; ++ks) {
            bf16x8 af[4], bfr[2];
            #pragma unroll
            for (int i = 0; i < 4; ++i) {
                const int row = wr * 64 + i * 16 + l15;
                af[i] = *(const bf16x8*)&As2[cur][row * 64 +
                            (((ks * 4 + quad) ^ (row & 7)) << 3)];
            }
            #pragma unroll
            for (int j = 0; j < 2; ++j) {
                const int nrw = wc * 32 + j * 16 + l15;
                bfr[j] = *(const bf16x8*)&Bs2[cur][nrw * 64 +
                            (((ks * 4 + quad) ^ (nrw & 7)) << 3)];
            }
            #pragma unroll
            for (int i = 0; i < 4; ++i)
                #pragma unroll
                for (int j = 0; j < 2; ++j)
                    acc[i][j] = MFMA16(af[i], bfr[j], acc[i][j]);
        }
        __syncthreads();    // drains next-tile gload_lds; one barrier per step
    }
    #undef OSTAGE

    #pragma unroll
    for (int i = 0; i < 4; ++i)
        #pragma unroll
        for (int r = 0; r < 4; ++r) {
            const int m = m0 + wr * 64 + i * 16 + quad * 4 + r;
            #pragma unroll
            for (int j = 0; j < 2; ++j) {
                const int n = n0 + wc * 32 + j * 16 + l15;
                Out[(size_t)m * H_ + n] = acc[i][j][r] + bias[n];
            }
        }
}

// ---------------------------------------------------------------------------
__global__ void fill_kernel(float* __restrict__ out, float val, int n) {
    const int i = blockIdx.x * 256 + threadIdx.x;
    if (i < n) out[i] = val;
}

// ---------------------------------------------------------------------------
extern "C" void kernel_launch(void* const* d_in, const int* in_sizes, int n_in,
                              void* d_out, int out_size, void* d_ws, size_t ws_size,
                              hipStream_t stream) {
    const float* q   = (const float*)d_in[0];
    const float* k   = (const float*)d_in[1];
    const float* v   = (const float*)d_in[2];
    const float* k_b = (const float*)d_in[3];
    const int*   msk = (const int*)d_in[4];
    const float* Wq  = (const float*)d_in[5];
    const float* bq  = (const float*)d_in[6];
    const float* Wk  = (const float*)d_in[7];
    const float* bk  = (const float*)d_in[8];
    const float* Wv  = (const float*)d_in[9];
    const float* bv  = (const float*)d_in[10];
    const float* Wkb = (const float*)d_in[11];
    const float* bkb = (const float*)d_in[12];
    const float* Wo  = (const float*)d_in[13];
    const float* bo  = (const float*)d_in[14];
    float* out = (float*)d_out;

    const size_t PER  = (size_t)B_ * NH_ * S_ * D_;
    const size_t NEED = 3 * PER * sizeof(unsigned short);   // 24 MiB (proven)
    if (ws_size < NEED) {   // tripwire (dead path)
        fill_kernel<<<(out_size + 255) / 256, 256, 0, stream>>>(
            out, (float)((ws_size >> 20) + 2), out_size);
        return;
    }
    unsigned short* wsh = (unsigned short*)d_ws;
    unsigned short* Qf  = wsh;              // Q head-major; becomes Hd after attn
    unsigned short* Kf  = wsh + PER;        // K' head-major; Wo_t scratch after attn
    unsigned short* Vf  = wsh + 2 * PER;    // V transposed [b,h,d,s]

    // d_out doubles as scratch for the 4 projection weights until out_mfma.
    unsigned short* Wt = (unsigned short*)d_out;

    dim3 gw(8, 8, 4);
    prep_w<<<gw, 256, 0, stream>>>(Wq, Wk, Wkb, Wv, Wt);

    // K first (16-step blocks), then Q/V (8-step): no inter-dependency, so
    // both co-schedule -> every CU carries a balanced long/short block mix.
    dim3 gk((B_ * S_) / 128, H_ / 128, 2);  // 64 x 4 x 2 = 512 blocks
    proj_k<<<gk, 256, 0, stream>>>(k, k_b, Wt, bk, bkb, Kf);

    dim3 gqv((B_ * S_) / 128, H_ / 128, 2); // 64 x 4 x 2 = 512 blocks
    proj_qv<<<gqv, 256, 0, stream>>>(q, v, Wt, bq, bv, Qf, Vf);

    dim3 ga(S_ / 64, NH_, B_);              // 32 x 8 x 4 = 1024 blocks
    attn_mfma<<<ga, 256, 0, stream>>>(Qf, Kf, Vf, msk);

    // Kf is dead after attn: reuse it for transposed Wo.
    dim3 gw1(8, 8, 1);
    prep_w<<<gw1, 256, 0, stream>>>(Wo, Wo, Wo, Wo, Kf);

    dim3 go((B_ * S_) / 128, H_ / 64, 1);   // 64 x 8 = 512 blocks
    out_mfma<<<go, 256, 0, stream>>>(Qf, Kf, bo, out);
}

// Round 9
// 239.274 us; speedup vs baseline: 1.3816x; 1.0686x over previous
//
#include <hip/hip_runtime.h>
#include <hip/hip_bf16.h>
#include <math.h>

#define B_  4
#define S_  2048
#define H_  512
#define NH_ 8
#define D_  64

typedef __attribute__((ext_vector_type(8))) short bf16x8;   // 8 bf16 = 4 VGPR
typedef __attribute__((ext_vector_type(4))) float f32x4;
typedef __attribute__((ext_vector_type(16))) float f32x16;
#define MFMA16(a, b, c) __builtin_amdgcn_mfma_f32_16x16x32_bf16(a, b, c, 0, 0, 0)
#define MFMA32(a, b, c) __builtin_amdgcn_mfma_f32_32x32x16_bf16(a, b, c, 0, 0, 0)

__device__ __forceinline__ unsigned short f2bf(float f) {
    union { float f; unsigned int i; } x; x.f = f;
    unsigned int i = x.i;
    i += 0x7fffu + ((i >> 16) & 1u);
    return (unsigned short)(i >> 16);
}
// packed fp32 pair -> bf16 pair (RNE), lo in low 16 bits
__device__ __forceinline__ unsigned int pk2(float lo, float hi) {
    union { __hip_bfloat162 h; unsigned int u; } c;
    c.h = __float22bfloat162_rn(make_float2(lo, hi));
    return c.u;
}
// async global->LDS, 16 B per lane; lds ptr must be wave-uniform
__device__ __forceinline__ void gl_lds16(const void* g, void* l) {
    __builtin_amdgcn_global_load_lds(
        (const __attribute__((address_space(1))) unsigned int*)g,
        (__attribute__((address_space(3))) unsigned int*)l, 16, 0, 0);
}

// ---------------------------------------------------------------------------
// Weight prep: transpose+convert 512x512 fp32 W -> bf16 Wt[n][k] (n-major).
// ---------------------------------------------------------------------------
__global__ __launch_bounds__(256) void prep_w(
    const float* __restrict__ W0, const float* __restrict__ W1,
    const float* __restrict__ W2, const float* __restrict__ W3,
    unsigned short* __restrict__ Wt)
{
    const float* Ws[4] = {W0, W1, W2, W3};
    const float* W = Ws[blockIdx.z];
    unsigned short* Y = Wt + (size_t)blockIdx.z * H_ * H_;
    __shared__ float Tl[64][68];
    const int t = threadIdx.x;
    const int k0 = blockIdx.y * 64, n0 = blockIdx.x * 64;
    #pragma unroll
    for (int i = 0; i < 4; ++i) {
        const int e = (t + 256 * i) * 4;
        const int r = e >> 6, c = e & 63;
        const float4 a = *(const float4*)(W + (size_t)(k0 + r) * H_ + n0 + c);
        Tl[c + 0][r] = a.x; Tl[c + 1][r] = a.y;
        Tl[c + 2][r] = a.z; Tl[c + 3][r] = a.w;
    }
    __syncthreads();
    #pragma unroll
    for (int i = 0; i < 4; ++i) {
        const int e = (t + 256 * i) * 4;
        const int n = e >> 6, c = e & 63;
        uint2 p;
        p.x = pk2(Tl[n][c + 0], Tl[n][c + 1]);
        p.y = pk2(Tl[n][c + 2], Tl[n][c + 3]);
        *(uint2*)(Y + (size_t)(n0 + n) * H_ + k0 + c) = p;
    }
}

// ---------------------------------------------------------------------------
// proj path A (VERIFIED in R8 as proj_qv): 128x128 tile, 8 K-steps.
// z==0 -> Q head-major epilogue; z==3 -> V transposed epilogue.
// ---------------------------------------------------------------------------
__device__ __forceinline__ void proj_tile128(
    const float* __restrict__ X, const unsigned short* __restrict__ Wp,
    const float* __restrict__ bias, unsigned short* __restrict__ Y,
    const bool VT, unsigned short* LB, const int m0, const int n0, const int t)
{
    unsigned short* As = LB;            // 8192 halfs [128][64] swz
    unsigned short* Bs = LB + 8192;     // 8192 halfs [128][64] swz
    const int w = t >> 6, lane = t & 63;
    const int quad = lane >> 4, l15 = lane & 15;
    const int wr = w >> 1, wc = w & 1;

    const f32x4 zero = {0.f, 0.f, 0.f, 0.f};
    f32x4 acc[4][4];
    #pragma unroll
    for (int i = 0; i < 4; ++i)
        #pragma unroll
        for (int j = 0; j < 4; ++j) acc[i][j] = zero;

    for (int kb0 = 0; kb0 < H_; kb0 += 64) {
        __syncthreads();
        #pragma unroll
        for (int i = 0; i < 4; ++i) {
            const int c = w * 4 + i;
            const int u = c * 64 + lane;
            const int row = u >> 3;
            const int sc  = ((u & 7) ^ (row & 7)) << 3;
            gl_lds16(Wp + (size_t)(n0 + row) * H_ + kb0 + sc, Bs + c * 512);
        }
        float4 av[8];
        #pragma unroll
        for (int i = 0; i < 8; ++i) {
            const int e = (t + 256 * i) * 4;
            av[i] = *(const float4*)(X + (size_t)(m0 + (e >> 6)) * H_ + kb0 + (e & 63));
        }
        #pragma unroll
        for (int i = 0; i < 8; ++i) {
            const int e = (t + 256 * i) * 4;
            const int row = e >> 6, kc = e & 63;
            uint2 p; p.x = pk2(av[i].x, av[i].y); p.y = pk2(av[i].z, av[i].w);
            *(uint2*)&As[row * 64 + ((((kc >> 3) ^ (row & 7)) << 3) | (kc & 7))] = p;
        }
        __syncthreads();
        #pragma unroll
        for (int ks = 0; ks < 2; ++ks) {
            bf16x8 af[4], bfr[4];
            #pragma unroll
            for (int i = 0; i < 4; ++i) {
                const int row = wr * 64 + i * 16 + l15;
                af[i] = *(const bf16x8*)&As[row * 64 +
                            (((ks * 4 + quad) ^ (row & 7)) << 3)];
            }
            #pragma unroll
            for (int j = 0; j < 4; ++j) {
                const int nrw = wc * 64 + j * 16 + l15;
                bfr[j] = *(const bf16x8*)&Bs[nrw * 64 +
                            (((ks * 4 + quad) ^ (nrw & 7)) << 3)];
            }
            #pragma unroll
            for (int i = 0; i < 4; ++i)
                #pragma unroll
                for (int j = 0; j < 4; ++j)
                    acc[i][j] = MFMA16(af[i], bfr[j], acc[i][j]);
        }
    }

    const int bb = m0 >> 11, s0 = m0 & (S_ - 1);
    if (!VT) {
        #pragma unroll
        for (int i = 0; i < 4; ++i)
            #pragma unroll
            for (int r = 0; r < 4; ++r) {
                const int s = s0 + wr * 64 + i * 16 + quad * 4 + r;
                #pragma unroll
                for (int j = 0; j < 4; ++j) {
                    const int nn = n0 + wc * 64 + j * 16 + l15;
                    const int h = nn >> 6, d = nn & 63;
                    Y[(((size_t)bb * NH_ + h) * S_ + s) * D_ + d] =
                        f2bf(acc[i][j][r] + bias[nn]);
                }
            }
    } else {
        __syncthreads();
        #pragma unroll
        for (int i = 0; i < 4; ++i)
            #pragma unroll
            for (int r = 0; r < 4; ++r) {
                const int ml = wr * 64 + i * 16 + quad * 4 + r;
                #pragma unroll
                for (int j = 0; j < 4; ++j) {
                    const int nl = wc * 64 + j * 16 + l15;
                    LB[nl * 136 + ml] = f2bf(acc[i][j][r] + bias[n0 + nl]);
                }
            }
        __syncthreads();
        const int nr = t >> 1, half = t & 1;
        const int nn = n0 + nr, h = nn >> 6, d = nn & 63;
        const size_t vbase = (((size_t)bb * NH_ + h) * D_ + d) * S_ + s0 + half * 64;
        #pragma unroll
        for (int i = 0; i < 16; ++i)
            *(ushort4*)(Y + vbase + i * 4) =
                *(const ushort4*)&LB[nr * 136 + half * 64 + i * 4];
    }
}

// ---------------------------------------------------------------------------
// proj path B (VERIFIED in R8 as proj_k): K-dual 64x128 tile, 16 K-steps
// pass-major (all Wk then all Wkb -- accumulation order identical to R6).
// ---------------------------------------------------------------------------
__device__ __forceinline__ void proj_tile64_dual(
    const float* __restrict__ k, const float* __restrict__ k_b,
    const unsigned short* __restrict__ Wkt, const unsigned short* __restrict__ Wkbt,
    const float* __restrict__ bk, const float* __restrict__ bkb,
    unsigned short* __restrict__ Kf, unsigned short* LB,
    const int m0, const int n0, const int t)
{
    unsigned short* As = LB;            // 4096 halfs [64][64] swz
    unsigned short* Bs = LB + 8192;     // 8192 halfs [128][64] swz
    const int w = t >> 6, lane = t & 63;
    const int quad = lane >> 4, l15 = lane & 15;
    const int wr = w >> 1, wc = w & 1;

    const f32x4 zero = {0.f, 0.f, 0.f, 0.f};
    f32x4 acc[2][4];
    #pragma unroll
    for (int i = 0; i < 2; ++i)
        #pragma unroll
        for (int j = 0; j < 4; ++j) acc[i][j] = zero;

    for (int p = 0; p < 2; ++p) {
        const float* Xp = p ? k_b : k;
        const unsigned short* Wp = p ? Wkbt : Wkt;
        for (int kb0 = 0; kb0 < H_; kb0 += 64) {
            __syncthreads();
            #pragma unroll
            for (int i = 0; i < 4; ++i) {
                const int c = w * 4 + i;
                const int u = c * 64 + lane;
                const int row = u >> 3;
                const int sc = ((u & 7) ^ (row & 7)) << 3;
                gl_lds16(Wp + (size_t)(n0 + row) * H_ + kb0 + sc, Bs + c * 512);
            }
            float4 av[4];
            #pragma unroll
            for (int i = 0; i < 4; ++i) {
                const int e = (t + 256 * i) * 4;
                av[i] = *(const float4*)(Xp + (size_t)(m0 + (e >> 6)) * H_ + kb0 + (e & 63));
            }
            #pragma unroll
            for (int i = 0; i < 4; ++i) {
                const int e = (t + 256 * i) * 4;
                const int row = e >> 6, kc = e & 63;
                uint2 pr; pr.x = pk2(av[i].x, av[i].y); pr.y = pk2(av[i].z, av[i].w);
                *(uint2*)&As[row * 64 + ((((kc >> 3) ^ (row & 7)) << 3) | (kc & 7))] = pr;
            }
            __syncthreads();
            #pragma unroll
            for (int ks = 0; ks < 2; ++ks) {
                bf16x8 af[2], bfr[4];
                #pragma unroll
                for (int i = 0; i < 2; ++i) {
                    const int row = wr * 32 + i * 16 + l15;
                    af[i] = *(const bf16x8*)&As[row * 64 +
                                (((ks * 4 + quad) ^ (row & 7)) << 3)];
                }
                #pragma unroll
                for (int j = 0; j < 4; ++j) {
                    const int nrw = wc * 64 + j * 16 + l15;
                    bfr[j] = *(const bf16x8*)&Bs[nrw * 64 +
                                (((ks * 4 + quad) ^ (nrw & 7)) << 3)];
                }
                #pragma unroll
                for (int i = 0; i < 2; ++i)
                    #pragma unroll
                    for (int j = 0; j < 4; ++j)
                        acc[i][j] = MFMA16(af[i], bfr[j], acc[i][j]);
            }
        }
    }

    const int bb = m0 >> 11, s0 = m0 & (S_ - 1);
    #pragma unroll
    for (int i = 0; i < 2; ++i)
        #pragma unroll
        for (int r = 0; r < 4; ++r) {
            const int s = s0 + wr * 32 + i * 16 + quad * 4 + r;
            #pragma unroll
            for (int j = 0; j < 4; ++j) {
                const int nn = n0 + wc * 64 + j * 16 + l15;
                const int h = nn >> 6, d = nn & 63;
                const float val = acc[i][j][r] + bk[nn] + bkb[nn];
                Kf[(((size_t)bb * NH_ + h) * S_ + s) * D_ + d] = f2bf(val);
            }
        }
}

// ---------------------------------------------------------------------------
// Fused projections v5 -- BALANCED, single dispatch. Grid (64,4,4):
//   z=0: Q     (path A, 8 steps x 32 MFMA)
//   z=1: K-lo  (path B, rows x*128..+64,    16 steps x 16 MFMA)
//   z=2: K-hi  (path B, rows x*128+64..+128,16 steps x 16 MFMA)
//   z=3: V     (path A + transposed epilogue)
// 1024 blocks = exactly 4/CU (LDS 34.8KB), one of each z per CU: equal
// per-block work (256 MFMA-units) -> no drained-wave tail, 4-deep TLP.
// Paths are separate forceinline bodies with compile-time bounds (R7's
// runtime-guarded unrolls spilled to scratch; R8 verified both paths).
// ---------------------------------------------------------------------------
__global__ __launch_bounds__(256, 4) void proj_all(
    const float* __restrict__ q,  const float* __restrict__ k,
    const float* __restrict__ v,  const float* __restrict__ k_b,
    const unsigned short* __restrict__ Wt,
    const float* __restrict__ bq, const float* __restrict__ bk,
    const float* __restrict__ bkb,const float* __restrict__ bv,
    unsigned short* __restrict__ Qf, unsigned short* __restrict__ Kf,
    unsigned short* __restrict__ Vf)
{
    __shared__ __align__(16) unsigned short LB[17408];
    const int z = blockIdx.z;
    const int t = threadIdx.x;
    const size_t WSZ = (size_t)H_ * H_;
    const int n0 = blockIdx.y * 128;

    if (z == 1 || z == 2) {
        const int m0 = blockIdx.x * 128 + (z - 1) * 64;
        proj_tile64_dual(k, k_b, Wt + WSZ, Wt + 2 * WSZ, bk, bkb, Kf,
                         LB, m0, n0, t);
    } else if (z == 0) {
        proj_tile128(q, Wt, bq, Qf, false, LB, blockIdx.x * 128, n0, t);
    } else {
        proj_tile128(v, Wt + 3 * WSZ, bv, Vf, true, LB, blockIdx.x * 128, n0, t);
    }
}

// ---------------------------------------------------------------------------
// MFMA flash attention v5 (unchanged control): key-split waves + lsum on the
// MFMA pipe via ones-MFMA.
// ---------------------------------------------------------------------------
__global__ __launch_bounds__(256, 4) void attn_mfma(
    unsigned short* QHd,
    const unsigned short* __restrict__ Kh, const unsigned short* __restrict__ Vt,
    const int* __restrict__ mask)
{
    const int b = blockIdx.z, h = blockIdx.y;
    const int q0 = blockIdx.x * 64;
    const int t = threadIdx.x;
    const int w = t >> 6, lane = t & 63;
    const int hi = lane >> 5, l31 = lane & 31;
    const int qg = w & 1, kh = w >> 1;

    __shared__ __align__(16) unsigned short KsL[2 * 4096];  // [2][64 key][64 d] swz
    __shared__ __align__(16) unsigned short VsL[2 * 4096];  // [2][64 d][64 key] swz
    __shared__ float mskf[S_];                              // -1e9 / 0 per key

    const size_t head = ((size_t)b * NH_ + h) * S_;
    unsigned short* Qbase = QHd + head * D_;
    const unsigned short* Kbase = Kh + head * D_;
    const unsigned short* Vbase = Vt + head * D_;   // [d][s] per head

    for (int i = t; i < S_; i += 256)
        mskf[i] = (mask[b * S_ + i] == 0) ? -1e9f : 0.f;

    bf16x8 qf[4];
    #pragma unroll
    for (int ks = 0; ks < 4; ++ks)
        qf[ks] = *(const bf16x8*)(
            Qbase + (size_t)(q0 + qg * 32 + l31) * D_ + ks * 16 + hi * 8);

    bf16x8 onesA;
    #pragma unroll
    for (int i = 0; i < 8; ++i) onesA[i] = (short)0x3F80;

    f32x16 O0, O1, O2;
    #pragma unroll
    for (int i = 0; i < 16; ++i) { O0[i] = 0.f; O1[i] = 0.f; O2[i] = 0.f; }
    const float SC2 = 0.125f * 1.44269504089f;      // 1/sqrt(D) * log2(e)

    #define STAGE(kt_) do {                                                        \
        const int bf_ = (kt_) & 1, k0_ = (kt_) * 64;                               \
        _Pragma("unroll")                                                          \
        for (int i_ = 0; i_ < 2; ++i_) {                                           \
            const int c_ = w * 2 + i_;                                             \
            const int u_ = c_ * 64 + lane;                                         \
            const int row_ = u_ >> 3;                                              \
            const int sc_ = ((u_ & 7) ^ (row_ & 7)) << 3;                          \
            gl_lds16(Kbase + (size_t)(k0_ + row_) * D_ + sc_,                      \
                     KsL + bf_ * 4096 + c_ * 512);                                 \
            gl_lds16(Vbase + (size_t)row_ * S_ + k0_ + sc_,                        \
                     VsL + bf_ * 4096 + c_ * 512);                                 \
        }                                                                          \
    } while (0)

    STAGE(0);
    __syncthreads();

    for (int kt = 0; kt < S_ / 64; ++kt) {
        const int bf = kt & 1;
        const int k0 = kt * 64;
        if (kt + 1 < S_ / 64) STAGE(kt + 1);

        f32x16 acc;
        #pragma unroll
        for (int i = 0; i < 16; ++i) acc[i] = 0.f;
        const int krow = kh * 32 + l31;
        const unsigned short* Kb = KsL + bf * 4096 + krow * 64;
        const int rwk = krow & 7;
        __builtin_amdgcn_s_setprio(1);
        #pragma unroll
        for (int ks = 0; ks < 4; ++ks) {
            const bf16x8 kf = *(const bf16x8*)&Kb[(((ks * 2 + hi) ^ rwk) << 3)];
            acc = MFMA32(kf, qf[ks], acc);
        }
        __builtin_amdgcn_s_setprio(0);
        float p[16];
        #pragma unroll
        for (int bq = 0; bq < 4; ++bq) {
            const float4 ms4 = *(const float4*)&mskf[k0 + kh * 32 + bq * 8 + hi * 4];
            p[4 * bq + 0] = __builtin_amdgcn_exp2f(fmaf(acc[4 * bq + 0], SC2, ms4.x));
            p[4 * bq + 1] = __builtin_amdgcn_exp2f(fmaf(acc[4 * bq + 1], SC2, ms4.y));
            p[4 * bq + 2] = __builtin_amdgcn_exp2f(fmaf(acc[4 * bq + 2], SC2, ms4.z));
            p[4 * bq + 3] = __builtin_amdgcn_exp2f(fmaf(acc[4 * bq + 3], SC2, ms4.w));
        }
        unsigned pkv[8];
        #pragma unroll
        for (int bq = 0; bq < 4; ++bq) {
            pkv[2 * bq + 0] = pk2(p[4 * bq + 0], p[4 * bq + 1]);
            pkv[2 * bq + 1] = pk2(p[4 * bq + 2], p[4 * bq + 3]);
        }
        bf16x8 pfrag[2];
        #pragma unroll
        for (int ksl = 0; ksl < 2; ++ksl) {
            unsigned m0 = pkv[4 * ksl + 0], m2 = pkv[4 * ksl + 2];
            asm volatile("v_permlane32_swap_b32 %0, %1" : "+v"(m0), "+v"(m2));
            unsigned m1 = pkv[4 * ksl + 1], m3 = pkv[4 * ksl + 3];
            asm volatile("v_permlane32_swap_b32 %0, %1" : "+v"(m1), "+v"(m3));
            union { unsigned u[4]; bf16x8 v; } pu;
            pu.u[0] = m0; pu.u[1] = m1; pu.u[2] = m2; pu.u[3] = m3;
            pfrag[ksl] = pu.v;
        }
        __builtin_amdgcn_s_setprio(1);
        #pragma unroll
        for (int dblk = 0; dblk < 2; ++dblk) {
            const int vrow = dblk * 32 + l31;
            const unsigned short* Vb = VsL + bf * 4096 + vrow * 64;
            const int rwv = vrow & 7;
            #pragma unroll
            for (int ksl = 0; ksl < 2; ++ksl) {
                const bf16x8 vf =
                    *(const bf16x8*)&Vb[(((kh * 4 + ksl * 2 + hi) ^ rwv) << 3)];
                if (dblk == 0) O0 = MFMA32(vf, pfrag[ksl], O0);
                else           O1 = MFMA32(vf, pfrag[ksl], O1);
            }
        }
        O2 = MFMA32(onesA, pfrag[0], O2);
        O2 = MFMA32(onesA, pfrag[1], O2);
        __builtin_amdgcn_s_setprio(0);
        __syncthreads();                        // single barrier per tile
    }
    #undef STAGE

    float lsum = O2[0];

    if (kh == 1) {
        float* R = qg ? (float*)VsL : (float*)KsL;
        #pragma unroll
        for (int i = 0; i < 16; ++i) R[lane * 33 + i]      = O0[i];
        #pragma unroll
        for (int i = 0; i < 16; ++i) R[lane * 33 + 16 + i] = O1[i];
        if (hi == 0) R[2112 + l31] = lsum;
    }
    __syncthreads();
    if (kh == 0) {
        const float* R = qg ? (const float*)VsL : (const float*)KsL;
        #pragma unroll
        for (int i = 0; i < 16; ++i) O0[i] += R[lane * 33 + i];
        #pragma unroll
        for (int i = 0; i < 16; ++i) O1[i] += R[lane * 33 + 16 + i];
        lsum += R[2112 + l31];
        const float inv = 1.f / lsum;

        unsigned short* Orow = Qbase + (size_t)(q0 + qg * 32 + l31) * D_;
        #pragma unroll
        for (int dblk = 0; dblk < 2; ++dblk) {
            #pragma unroll
            for (int bq = 0; bq < 4; ++bq) {
                const float v0 = (dblk ? O1[4 * bq + 0] : O0[4 * bq + 0]) * inv;
                const float v1 = (dblk ? O1[4 * bq + 1] : O0[4 * bq + 1]) * inv;
                const float v2 = (dblk ? O1[4 * bq + 2] : O0[4 * bq + 2]) * inv;
                const float v3 = (dblk ? O1[4 * bq + 3] : O0[4 * bq + 3]) * inv;
                uint2 st; st.x = pk2(v0, v1); st.y = pk2(v2, v3);
                *(uint2*)&Orow[dblk * 32 + bq * 8 + hi * 4] = st;
            }
        }
    }
}

// ---------------------------------------------------------------------------
// MFMA output GEMM (R5/R6-proven dbuf): Out_f32[m,n] = Hd@Wo + bo.
// Both tiles gload_lds; double-buffered, ONE barrier per K-step. 128x64
// tiles, grid (64,8) = 512 blocks (grid-limited 2/CU -> 48KB LDS is free).
// ---------------------------------------------------------------------------
__global__ __launch_bounds__(256) void out_mfma(
    const unsigned short* __restrict__ Hd, const unsigned short* __restrict__ Wot,
    const float* __restrict__ bias, float* __restrict__ Out)
{
    __shared__ __align__(16) unsigned short As2[2][8192];   // [128][64] swz
    __shared__ __align__(16) unsigned short Bs2[2][4096];   // [64][64] swz
    const int t = threadIdx.x;
    const int w = t >> 6, lane = t & 63;
    const int quad = lane >> 4, l15 = lane & 15;
    const int wr = w >> 1, wc = w & 1;
    const int m0 = blockIdx.x * 128, n0 = blockIdx.y * 64;
    const int bb = m0 >> 11, s0 = m0 & (S_ - 1);

    const f32x4 zero = {0.f, 0.f, 0.f, 0.f};
    f32x4 acc[4][2];
    #pragma unroll
    for (int i = 0; i < 4; ++i)
        #pragma unroll
        for (int j = 0; j < 2; ++j) acc[i][j] = zero;

    #define OSTAGE(s_, bfx_) do {                                              \
        const int hk_ = (s_);                                                  \
        const unsigned short* Ab_ = Hd + (((size_t)bb * NH_ + hk_) * S_ + s0)  \
                                    * D_;                                      \
        _Pragma("unroll")                                                      \
        for (int i_ = 0; i_ < 4; ++i_) {                                       \
            const int c_ = w * 4 + i_, u_ = c_ * 64 + lane, row_ = u_ >> 3;    \
            const int sc_ = ((u_ & 7) ^ (row_ & 7)) << 3;                      \
            gl_lds16(Ab_ + (size_t)row_ * D_ + sc_, As2[bfx_] + c_ * 512);     \
        }                                                                      \
        _Pragma("unroll")                                                      \
        for (int i_ = 0; i_ < 2; ++i_) {                                       \
            const int c_ = w * 2 + i_, u_ = c_ * 64 + lane, row_ = u_ >> 3;    \
            const int sc_ = ((u_ & 7) ^ (row_ & 7)) << 3;                      \
            gl_lds16(Wot + (size_t)(n0 + row_) * H_ + hk_ * 64 + sc_,          \
                     Bs2[bfx_] + c_ * 512);                                    \
        }                                                                      \
    } while (0)

    OSTAGE(0, 0);
    __syncthreads();

    for (int s = 0; s < 8; ++s) {
        const int cur = s & 1;
        if (s + 1 < 8) OSTAGE(s + 1, cur ^ 1);
        #pragma unroll
        for (int ks = 0; ks < 2; ++ks) {
            bf16x8 af[4], bfr[2];
            #pragma unroll
            for (int i = 0; i < 4; ++i) {
                const int row = wr * 64 + i * 16 + l15;
                af[i] = *(const bf16x8*)&As2[cur][row * 64 +
                            (((ks * 4 + quad) ^ (row & 7)) << 3)];
            }
            #pragma unroll
            for (int j = 0; j < 2; ++j) {
                const int nrw = wc * 32 + j * 16 + l15;
                bfr[j] = *(const bf16x8*)&Bs2[cur][nrw * 64 +
                            (((ks * 4 + quad) ^ (nrw & 7)) << 3)];
            }
            #pragma unroll
            for (int i = 0; i < 4; ++i)
                #pragma unroll
                for (int j = 0; j < 2; ++j)
                    acc[i][j] = MFMA16(af[i], bfr[j], acc[i][j]);
        }
        __syncthreads();    // drains next-tile gload_lds; one barrier per step
    }
    #undef OSTAGE

    #pragma unroll
    for (int i = 0; i < 4; ++i)
        #pragma unroll
        for (int r = 0; r < 4; ++r) {
            const int m = m0 + wr * 64 + i * 16 + quad * 4 + r;
            #pragma unroll
            for (int j = 0; j < 2; ++j) {
                const int n = n0 + wc * 32 + j * 16 + l15;
                Out[(size_t)m * H_ + n] = acc[i][j][r] + bias[n];
            }
        }
}

// ---------------------------------------------------------------------------
__global__ void fill_kernel(float* __restrict__ out, float val, int n) {
    const int i = blockIdx.x * 256 + threadIdx.x;
    if (i < n) out[i] = val;
}

// ---------------------------------------------------------------------------
extern "C" void kernel_launch(void* const* d_in, const int* in_sizes, int n_in,
                              void* d_out, int out_size, void* d_ws, size_t ws_size,
                              hipStream_t stream) {
    const float* q   = (const float*)d_in[0];
    const float* k   = (const float*)d_in[1];
    const float* v   = (const float*)d_in[2];
    const float* k_b = (const float*)d_in[3];
    const int*   msk = (const int*)d_in[4];
    const float* Wq  = (const float*)d_in[5];
    const float* bq  = (const float*)d_in[6];
    const float* Wk  = (const float*)d_in[7];
    const float* bk  = (const float*)d_in[8];
    const float* Wv  = (const float*)d_in[9];
    const float* bv  = (const float*)d_in[10];
    const float* Wkb = (const float*)d_in[11];
    const float* bkb = (const float*)d_in[12];
    const float* Wo  = (const float*)d_in[13];
    const float* bo  = (const float*)d_in[14];
    float* out = (float*)d_out;

    const size_t PER  = (size_t)B_ * NH_ * S_ * D_;
    const size_t NEED = 3 * PER * sizeof(unsigned short);   // 24 MiB (proven)
    if (ws_size < NEED) {   // tripwire (dead path)
        fill_kernel<<<(out_size + 255) / 256, 256, 0, stream>>>(
            out, (float)((ws_size >> 20) + 2), out_size);
        return;
    }
    unsigned short* wsh = (unsigned short*)d_ws;
    unsigned short* Qf  = wsh;              // Q head-major; becomes Hd after attn
    unsigned short* Kf  = wsh + PER;        // K' head-major; Wo_t scratch after attn
    unsigned short* Vf  = wsh + 2 * PER;    // V transposed [b,h,d,s]

    // d_out doubles as scratch for the 4 projection weights until out_mfma.
    unsigned short* Wt = (unsigned short*)d_out;

    dim3 gw(8, 8, 4);
    prep_w<<<gw, 256, 0, stream>>>(Wq, Wk, Wkb, Wv, Wt);

    dim3 gp((B_ * S_) / 128, H_ / 128, 4);  // 64 x 4 x 4 = 1024 balanced blocks
    proj_all<<<gp, 256, 0, stream>>>(q, k, v, k_b, Wt, bq, bk, bkb, bv, Qf, Kf, Vf);

    dim3 ga(S_ / 64, NH_, B_);              // 32 x 8 x 4 = 1024 blocks
    attn_mfma<<<ga, 256, 0, stream>>>(Qf, Kf, Vf, msk);

    // Kf is dead after attn: reuse it for transposed Wo.
    dim3 gw1(8, 8, 1);
    prep_w<<<gw1, 256, 0, stream>>>(Wo, Wo, Wo, Wo, Kf);

    dim3 go((B_ * S_) / 128, H_ / 64, 1);   // 64 x 8 = 512 blocks
    out_mfma<<<go, 256, 0, stream>>>(Qf, Kf, bo, out);
}

// Round 10
// 227.442 us; speedup vs baseline: 1.4535x; 1.0520x over previous
//
#include <hip/hip_runtime.h>
#include <hip/hip_bf16.h>
#include <math.h>

#define B_  4
#define S_  2048
#define H_  512
#define NH_ 8
#define D_  64

typedef __attribute__((ext_vector_type(8))) short bf16x8;   // 8 bf16 = 4 VGPR
typedef __attribute__((ext_vector_type(4))) float f32x4;
typedef __attribute__((ext_vector_type(16))) float f32x16;
#define MFMA16(a, b, c) __builtin_amdgcn_mfma_f32_16x16x32_bf16(a, b, c, 0, 0, 0)
#define MFMA32(a, b, c) __builtin_amdgcn_mfma_f32_32x32x16_bf16(a, b, c, 0, 0, 0)

__device__ __forceinline__ unsigned short f2bf(float f) {
    union { float f; unsigned int i; } x; x.f = f;
    unsigned int i = x.i;
    i += 0x7fffu + ((i >> 16) & 1u);
    return (unsigned short)(i >> 16);
}
// packed fp32 pair -> bf16 pair (RNE), lo in low 16 bits
__device__ __forceinline__ unsigned int pk2(float lo, float hi) {
    union { __hip_bfloat162 h; unsigned int u; } c;
    c.h = __float22bfloat162_rn(make_float2(lo, hi));
    return c.u;
}
// async global->LDS, 16 B per lane; lds ptr must be wave-uniform
__device__ __forceinline__ void gl_lds16(const void* g, void* l) {
    __builtin_amdgcn_global_load_lds(
        (const __attribute__((address_space(1))) unsigned int*)g,
        (__attribute__((address_space(3))) unsigned int*)l, 16, 0, 0);
}

// ---------------------------------------------------------------------------
// Weight prep: transpose+convert 512x512 fp32 W -> bf16 W^T[n][k] (n-major).
// z<4 -> Wt + z*H*H ; z==4 -> Wot (separate buffer). Grid (8, 8, nz).
// ---------------------------------------------------------------------------
__global__ __launch_bounds__(256) void prep_w(
    const float* __restrict__ W0, const float* __restrict__ W1,
    const float* __restrict__ W2, const float* __restrict__ W3,
    const float* __restrict__ W4,
    unsigned short* __restrict__ Wt, unsigned short* __restrict__ Wot)
{
    const float* Ws[5] = {W0, W1, W2, W3, W4};
    const float* W = Ws[blockIdx.z];
    unsigned short* Y = (blockIdx.z == 4)
        ? Wot : Wt + (size_t)blockIdx.z * H_ * H_;
    __shared__ float Tl[64][68];
    const int t = threadIdx.x;
    const int k0 = blockIdx.y * 64, n0 = blockIdx.x * 64;
    #pragma unroll
    for (int i = 0; i < 4; ++i) {
        const int e = (t + 256 * i) * 4;
        const int r = e >> 6, c = e & 63;
        const float4 a = *(const float4*)(W + (size_t)(k0 + r) * H_ + n0 + c);
        Tl[c + 0][r] = a.x; Tl[c + 1][r] = a.y;
        Tl[c + 2][r] = a.z; Tl[c + 3][r] = a.w;
    }
    __syncthreads();
    #pragma unroll
    for (int i = 0; i < 4; ++i) {
        const int e = (t + 256 * i) * 4;
        const int n = e >> 6, c = e & 63;
        uint2 p;
        p.x = pk2(Tl[n][c + 0], Tl[n][c + 1]);
        p.y = pk2(Tl[n][c + 2], Tl[n][c + 3]);
        *(uint2*)(Y + (size_t)(n0 + n) * H_ + k0 + c) = p;
    }
}

// ---------------------------------------------------------------------------
// Fused projections (R3/R5/R6-proven, best-measured config): z=0 Q,
// z=1 K (dual: k@Wk + k_b@Wkb), z=2 V (transposed epilogue -> Vt[b,h,d,s]).
// Tile 128x128, K-step 64, 2x2 wave quadrants. Single-buffered; B via
// global_load_lds + pre-swizzled source; A fp32->bf16 swizzled write.
// Structural rewrites all measured worse: dbuf (R4 +12), balanced-z
// (R9 +7), split launches (R8 +23), runtime-guarded unrolls (R7 spill).
// ---------------------------------------------------------------------------
__global__ __launch_bounds__(256, 3) void proj_all(
    const float* __restrict__ q,  const float* __restrict__ k,
    const float* __restrict__ v,  const float* __restrict__ k_b,
    const unsigned short* __restrict__ Wt,
    const float* __restrict__ bq, const float* __restrict__ bk,
    const float* __restrict__ bkb,const float* __restrict__ bv,
    unsigned short* __restrict__ Qf, unsigned short* __restrict__ Kf,
    unsigned short* __restrict__ Vf)
{
    __shared__ __align__(16) unsigned short LB[17408];
    unsigned short* As = LB;            // 8192 halfs
    unsigned short* Bs = LB + 8192;     // 8192 halfs

    const int z = blockIdx.z;
    const float *X, *bias, *X2 = nullptr, *bias2 = nullptr;
    const unsigned short *Wa, *Wb = nullptr;
    unsigned short* Y;
    bool VT = false;
    const size_t WSZ = (size_t)H_ * H_;
    if (z == 0)      { X = q; Wa = Wt;           bias = bq; Y = Qf; }
    else if (z == 1) { X = k; Wa = Wt + WSZ;     bias = bk;
                       X2 = k_b; Wb = Wt + 2 * WSZ; bias2 = bkb; Y = Kf; }
    else             { X = v; Wa = Wt + 3 * WSZ; bias = bv; Y = Vf; VT = true; }

    const int t = threadIdx.x;
    const int w = t >> 6, lane = t & 63;
    const int quad = lane >> 4, l15 = lane & 15;
    const int wr = w >> 1, wc = w & 1;
    const int m0 = blockIdx.x * 128, n0 = blockIdx.y * 128;

    const f32x4 zero = {0.f, 0.f, 0.f, 0.f};
    f32x4 acc[4][4];
    #pragma unroll
    for (int i = 0; i < 4; ++i)
        #pragma unroll
        for (int j = 0; j < 4; ++j) acc[i][j] = zero;

    const int npass = (X2 != nullptr) ? 2 : 1;
    for (int pass = 0; pass < npass; ++pass) {
        const float* Xp = pass ? X2 : X;
        const unsigned short* Wp = pass ? Wb : Wa;
        for (int kb0 = 0; kb0 < H_; kb0 += 64) {
            __syncthreads();
            #pragma unroll
            for (int i = 0; i < 4; ++i) {
                const int c = w * 4 + i;
                const int u = c * 64 + lane;
                const int row = u >> 3;
                const int sc  = ((u & 7) ^ (row & 7)) << 3;
                gl_lds16(Wp + (size_t)(n0 + row) * H_ + kb0 + sc, Bs + c * 512);
            }
            float4 av[8];
            #pragma unroll
            for (int i = 0; i < 8; ++i) {
                const int e = (t + 256 * i) * 4;
                av[i] = *(const float4*)(Xp + (size_t)(m0 + (e >> 6)) * H_ + kb0 + (e & 63));
            }
            #pragma unroll
            for (int i = 0; i < 8; ++i) {
                const int e = (t + 256 * i) * 4;
                const int row = e >> 6, kc = e & 63;
                uint2 p; p.x = pk2(av[i].x, av[i].y); p.y = pk2(av[i].z, av[i].w);
                *(uint2*)&As[row * 64 + ((((kc >> 3) ^ (row & 7)) << 3) | (kc & 7))] = p;
            }
            __syncthreads();
            #pragma unroll
            for (int ks = 0; ks < 2; ++ks) {
                bf16x8 af[4], bfr[4];
                #pragma unroll
                for (int i = 0; i < 4; ++i) {
                    const int row = wr * 64 + i * 16 + l15;
                    af[i] = *(const bf16x8*)&As[row * 64 +
                                (((ks * 4 + quad) ^ (row & 7)) << 3)];
                }
                #pragma unroll
                for (int j = 0; j < 4; ++j) {
                    const int nrw = wc * 64 + j * 16 + l15;
                    bfr[j] = *(const bf16x8*)&Bs[nrw * 64 +
                                (((ks * 4 + quad) ^ (nrw & 7)) << 3)];
                }
                #pragma unroll
                for (int i = 0; i < 4; ++i)
                    #pragma unroll
                    for (int j = 0; j < 4; ++j)
                        acc[i][j] = MFMA16(af[i], bfr[j], acc[i][j]);
            }
        }
    }

    const int bb = m0 >> 11, s0 = m0 & (S_ - 1);
    if (!VT) {
        #pragma unroll
        for (int i = 0; i < 4; ++i)
            #pragma unroll
            for (int r = 0; r < 4; ++r) {
                const int s = s0 + wr * 64 + i * 16 + quad * 4 + r;
                #pragma unroll
                for (int j = 0; j < 4; ++j) {
                    const int nn = n0 + wc * 64 + j * 16 + l15;
                    const int h = nn >> 6, d = nn & 63;
                    float val = acc[i][j][r] + bias[nn];
                    if (bias2) val += bias2[nn];
                    Y[(((size_t)bb * NH_ + h) * S_ + s) * D_ + d] = f2bf(val);
                }
            }
    } else {
        __syncthreads();
        #pragma unroll
        for (int i = 0; i < 4; ++i)
            #pragma unroll
            for (int r = 0; r < 4; ++r) {
                const int ml = wr * 64 + i * 16 + quad * 4 + r;
                #pragma unroll
                for (int j = 0; j < 4; ++j) {
                    const int nl = wc * 64 + j * 16 + l15;
                    LB[nl * 136 + ml] = f2bf(acc[i][j][r] + bias[n0 + nl]);
                }
            }
        __syncthreads();
        const int nr = t >> 1, half = t & 1;
        const int nn = n0 + nr, h = nn >> 6, d = nn & 63;
        const size_t vbase = (((size_t)bb * NH_ + h) * D_ + d) * S_ + s0 + half * 64;
        #pragma unroll
        for (int i = 0; i < 16; ++i)
            *(ushort4*)(Y + vbase + i * 4) =
                *(const ushort4*)&LB[nr * 136 + half * 64 + i * 4];
    }
}

// ---------------------------------------------------------------------------
// MFMA flash attention v5 (best-measured): key-split waves (4 blocks/CU,
// 16 waves/CU) + lsum on the MFMA pipe via ones-MFMA; in-register P via
// swapped QK^T + cvt_pk + permlane32_swap; K/V async-staged, XOR-swizzled.
// ---------------------------------------------------------------------------
__global__ __launch_bounds__(256, 4) void attn_mfma(
    unsigned short* QHd,
    const unsigned short* __restrict__ Kh, const unsigned short* __restrict__ Vt,
    const int* __restrict__ mask)
{
    const int b = blockIdx.z, h = blockIdx.y;
    const int q0 = blockIdx.x * 64;
    const int t = threadIdx.x;
    const int w = t >> 6, lane = t & 63;
    const int hi = lane >> 5, l31 = lane & 31;
    const int qg = w & 1, kh = w >> 1;

    __shared__ __align__(16) unsigned short KsL[2 * 4096];  // [2][64 key][64 d] swz
    __shared__ __align__(16) unsigned short VsL[2 * 4096];  // [2][64 d][64 key] swz
    __shared__ float mskf[S_];                              // -1e9 / 0 per key

    const size_t head = ((size_t)b * NH_ + h) * S_;
    unsigned short* Qbase = QHd + head * D_;
    const unsigned short* Kbase = Kh + head * D_;
    const unsigned short* Vbase = Vt + head * D_;   // [d][s] per head

    for (int i = t; i < S_; i += 256)
        mskf[i] = (mask[b * S_ + i] == 0) ? -1e9f : 0.f;

    bf16x8 qf[4];
    #pragma unroll
    for (int ks = 0; ks < 4; ++ks)
        qf[ks] = *(const bf16x8*)(
            Qbase + (size_t)(q0 + qg * 32 + l31) * D_ + ks * 16 + hi * 8);

    bf16x8 onesA;
    #pragma unroll
    for (int i = 0; i < 8; ++i) onesA[i] = (short)0x3F80;

    f32x16 O0, O1, O2;
    #pragma unroll
    for (int i = 0; i < 16; ++i) { O0[i] = 0.f; O1[i] = 0.f; O2[i] = 0.f; }
    const float SC2 = 0.125f * 1.44269504089f;      // 1/sqrt(D) * log2(e)

    #define STAGE(kt_) do {                                                        \
        const int bf_ = (kt_) & 1, k0_ = (kt_) * 64;                               \
        _Pragma("unroll")                                                          \
        for (int i_ = 0; i_ < 2; ++i_) {                                           \
            const int c_ = w * 2 + i_;                                             \
            const int u_ = c_ * 64 + lane;                                         \
            const int row_ = u_ >> 3;                                              \
            const int sc_ = ((u_ & 7) ^ (row_ & 7)) << 3;                          \
            gl_lds16(Kbase + (size_t)(k0_ + row_) * D_ + sc_,                      \
                     KsL + bf_ * 4096 + c_ * 512);                                 \
            gl_lds16(Vbase + (size_t)row_ * S_ + k0_ + sc_,                        \
                     VsL + bf_ * 4096 + c_ * 512);                                 \
        }                                                                          \
    } while (0)

    STAGE(0);
    __syncthreads();

    for (int kt = 0; kt < S_ / 64; ++kt) {
        const int bf = kt & 1;
        const int k0 = kt * 64;
        if (kt + 1 < S_ / 64) STAGE(kt + 1);

        f32x16 acc;
        #pragma unroll
        for (int i = 0; i < 16; ++i) acc[i] = 0.f;
        const int krow = kh * 32 + l31;
        const unsigned short* Kb = KsL + bf * 4096 + krow * 64;
        const int rwk = krow & 7;
        __builtin_amdgcn_s_setprio(1);
        #pragma unroll
        for (int ks = 0; ks < 4; ++ks) {
            const bf16x8 kf = *(const bf16x8*)&Kb[(((ks * 2 + hi) ^ rwk) << 3)];
            acc = MFMA32(kf, qf[ks], acc);
        }
        __builtin_amdgcn_s_setprio(0);
        float p[16];
        #pragma unroll
        for (int bq = 0; bq < 4; ++bq) {
            const float4 ms4 = *(const float4*)&mskf[k0 + kh * 32 + bq * 8 + hi * 4];
            p[4 * bq + 0] = __builtin_amdgcn_exp2f(fmaf(acc[4 * bq + 0], SC2, ms4.x));
            p[4 * bq + 1] = __builtin_amdgcn_exp2f(fmaf(acc[4 * bq + 1], SC2, ms4.y));
            p[4 * bq + 2] = __builtin_amdgcn_exp2f(fmaf(acc[4 * bq + 2], SC2, ms4.z));
            p[4 * bq + 3] = __builtin_amdgcn_exp2f(fmaf(acc[4 * bq + 3], SC2, ms4.w));
        }
        unsigned pkv[8];
        #pragma unroll
        for (int bq = 0; bq < 4; ++bq) {
            pkv[2 * bq + 0] = pk2(p[4 * bq + 0], p[4 * bq + 1]);
            pkv[2 * bq + 1] = pk2(p[4 * bq + 2], p[4 * bq + 3]);
        }
        bf16x8 pfrag[2];
        #pragma unroll
        for (int ksl = 0; ksl < 2; ++ksl) {
            unsigned m0 = pkv[4 * ksl + 0], m2 = pkv[4 * ksl + 2];
            asm volatile("v_permlane32_swap_b32 %0, %1" : "+v"(m0), "+v"(m2));
            unsigned m1 = pkv[4 * ksl + 1], m3 = pkv[4 * ksl + 3];
            asm volatile("v_permlane32_swap_b32 %0, %1" : "+v"(m1), "+v"(m3));
            union { unsigned u[4]; bf16x8 v; } pu;
            pu.u[0] = m0; pu.u[1] = m1; pu.u[2] = m2; pu.u[3] = m3;
            pfrag[ksl] = pu.v;
        }
        __builtin_amdgcn_s_setprio(1);
        #pragma unroll
        for (int dblk = 0; dblk < 2; ++dblk) {
            const int vrow = dblk * 32 + l31;
            const unsigned short* Vb = VsL + bf * 4096 + vrow * 64;
            const int rwv = vrow & 7;
            #pragma unroll
            for (int ksl = 0; ksl < 2; ++ksl) {
                const bf16x8 vf =
                    *(const bf16x8*)&Vb[(((kh * 4 + ksl * 2 + hi) ^ rwv) << 3)];
                if (dblk == 0) O0 = MFMA32(vf, pfrag[ksl], O0);
                else           O1 = MFMA32(vf, pfrag[ksl], O1);
            }
        }
        O2 = MFMA32(onesA, pfrag[0], O2);
        O2 = MFMA32(onesA, pfrag[1], O2);
        __builtin_amdgcn_s_setprio(0);
        __syncthreads();                        // single barrier per tile
    }
    #undef STAGE

    float lsum = O2[0];

    if (kh == 1) {
        float* R = qg ? (float*)VsL : (float*)KsL;
        #pragma unroll
        for (int i = 0; i < 16; ++i) R[lane * 33 + i]      = O0[i];
        #pragma unroll
        for (int i = 0; i < 16; ++i) R[lane * 33 + 16 + i] = O1[i];
        if (hi == 0) R[2112 + l31] = lsum;
    }
    __syncthreads();
    if (kh == 0) {
        const float* R = qg ? (const float*)VsL : (const float*)KsL;
        #pragma unroll
        for (int i = 0; i < 16; ++i) O0[i] += R[lane * 33 + i];
        #pragma unroll
        for (int i = 0; i < 16; ++i) O1[i] += R[lane * 33 + 16 + i];
        lsum += R[2112 + l31];
        const float inv = 1.f / lsum;

        unsigned short* Orow = Qbase + (size_t)(q0 + qg * 32 + l31) * D_;
        #pragma unroll
        for (int dblk = 0; dblk < 2; ++dblk) {
            #pragma unroll
            for (int bq = 0; bq < 4; ++bq) {
                const float v0 = (dblk ? O1[4 * bq + 0] : O0[4 * bq + 0]) * inv;
                const float v1 = (dblk ? O1[4 * bq + 1] : O0[4 * bq + 1]) * inv;
                const float v2 = (dblk ? O1[4 * bq + 2] : O0[4 * bq + 2]) * inv;
                const float v3 = (dblk ? O1[4 * bq + 3] : O0[4 * bq + 3]) * inv;
                uint2 st; st.x = pk2(v0, v1); st.y = pk2(v2, v3);
                *(uint2*)&Orow[dblk * 32 + bq * 8 + hi * 4] = st;
            }
        }
    }
}

// ---------------------------------------------------------------------------
// MFMA output GEMM (R5/R6-proven dbuf): Out_f32[m,n] = Hd@Wo + bo.
// Both tiles gload_lds; double-buffered, ONE barrier per K-step. 128x64
// tiles, grid (64,8) = 512 blocks (grid-limited 2/CU -> 48KB LDS is free).
// ---------------------------------------------------------------------------
__global__ __launch_bounds__(256) void out_mfma(
    const unsigned short* __restrict__ Hd, const unsigned short* __restrict__ Wot,
    const float* __restrict__ bias, float* __restrict__ Out)
{
    __shared__ __align__(16) unsigned short As2[2][8192];   // [128][64] swz
    __shared__ __align__(16) unsigned short Bs2[2][4096];   // [64][64] swz
    const int t = threadIdx.x;
    const int w = t >> 6, lane = t & 63;
    const int quad = lane >> 4, l15 = lane & 15;
    const int wr = w >> 1, wc = w & 1;
    const int m0 = blockIdx.x * 128, n0 = blockIdx.y * 64;
    const int bb = m0 >> 11, s0 = m0 & (S_ - 1);

    const f32x4 zero = {0.f, 0.f, 0.f, 0.f};
    f32x4 acc[4][2];
    #pragma unroll
    for (int i = 0; i < 4; ++i)
        #pragma unroll
        for (int j = 0; j < 2; ++j) acc[i][j] = zero;

    #define OSTAGE(s_, bfx_) do {                                              \
        const int hk_ = (s_);                                                  \
        const unsigned short* Ab_ = Hd + (((size_t)bb * NH_ + hk_) * S_ + s0)  \
                                    * D_;                                      \
        _Pragma("unroll")                                                      \
        for (int i_ = 0; i_ < 4; ++i_) {                                       \
            const int c_ = w * 4 + i_, u_ = c_ * 64 + lane, row_ = u_ >> 3;    \
            const int sc_ = ((u_ & 7) ^ (row_ & 7)) << 3;                      \
            gl_lds16(Ab_ + (size_t)row_ * D_ + sc_, As2[bfx_] + c_ * 512);     \
        }                                                                      \
        _Pragma("unroll")                                                      \
        for (int i_ = 0; i_ < 2; ++i_) {                                       \
            const int c_ = w * 2 + i_, u_ = c_ * 64 + lane, row_ = u_ >> 3;    \
            const int sc_ = ((u_ & 7) ^ (row_ & 7)) << 3;                      \
            gl_lds16(Wot + (size_t)(n0 + row_) * H_ + hk_ * 64 + sc_,          \
                     Bs2[bfx_] + c_ * 512);                                    \
        }                                                                      \
    } while (0)

    OSTAGE(0, 0);
    __syncthreads();

    for (int s = 0; s < 8; ++s) {
        const int cur = s & 1;
        if (s + 1 < 8) OSTAGE(s + 1, cur ^ 1);
        #pragma unroll
        for (int ks = 0; ks < 2; ++ks) {
            bf16x8 af[4], bfr[2];
            #pragma unroll
            for (int i = 0; i < 4; ++i) {
                const int row = wr * 64 + i * 16 + l15;
                af[i] = *(const bf16x8*)&As2[cur][row * 64 +
                            (((ks * 4 + quad) ^ (row & 7)) << 3)];
            }
            #pragma unroll
            for (int j = 0; j < 2; ++j) {
                const int nrw = wc * 32 + j * 16 + l15;
                bfr[j] = *(const bf16x8*)&Bs2[cur][nrw * 64 +
                            (((ks * 4 + quad) ^ (nrw & 7)) << 3)];
            }
            #pragma unroll
            for (int i = 0; i < 4; ++i)
                #pragma unroll
                for (int j = 0; j < 2; ++j)
                    acc[i][j] = MFMA16(af[i], bfr[j], acc[i][j]);
        }
        __syncthreads();    // drains next-tile gload_lds; one barrier per step
    }
    #undef OSTAGE

    #pragma unroll
    for (int i = 0; i < 4; ++i)
        #pragma unroll
        for (int r = 0; r < 4; ++r) {
            const int m = m0 + wr * 64 + i * 16 + quad * 4 + r;
            #pragma unroll
            for (int j = 0; j < 2; ++j) {
                const int n = n0 + wc * 32 + j * 16 + l15;
                Out[(size_t)m * H_ + n] = acc[i][j][r] + bias[n];
            }
        }
}

// ---------------------------------------------------------------------------
__global__ void fill_kernel(float* __restrict__ out, float val, int n) {
    const int i = blockIdx.x * 256 + threadIdx.x;
    if (i < n) out[i] = val;
}

// ---------------------------------------------------------------------------
extern "C" void kernel_launch(void* const* d_in, const int* in_sizes, int n_in,
                              void* d_out, int out_size, void* d_ws, size_t ws_size,
                              hipStream_t stream) {
    const float* q   = (const float*)d_in[0];
    const float* k   = (const float*)d_in[1];
    const float* v   = (const float*)d_in[2];
    const float* k_b = (const float*)d_in[3];
    const int*   msk = (const int*)d_in[4];
    const float* Wq  = (const float*)d_in[5];
    const float* bq  = (const float*)d_in[6];
    const float* Wk  = (const float*)d_in[7];
    const float* bk  = (const float*)d_in[8];
    const float* Wv  = (const float*)d_in[9];
    const float* bv  = (const float*)d_in[10];
    const float* Wkb = (const float*)d_in[11];
    const float* bkb = (const float*)d_in[12];
    const float* Wo  = (const float*)d_in[13];
    const float* bo  = (const float*)d_in[14];
    float* out = (float*)d_out;

    const size_t PER  = (size_t)B_ * NH_ * S_ * D_;
    const size_t NEED = 3 * PER * sizeof(unsigned short);   // 24 MiB (proven)
    if (ws_size < NEED) {   // tripwire (dead path)
        fill_kernel<<<(out_size + 255) / 256, 256, 0, stream>>>(
            out, (float)((ws_size >> 20) + 2), out_size);
        return;
    }
    unsigned short* wsh = (unsigned short*)d_ws;
    unsigned short* Qf  = wsh;              // Q head-major; becomes Hd after attn
    unsigned short* Kf  = wsh + PER;        // K' head-major
    unsigned short* Vf  = wsh + 2 * PER;    // V transposed [b,h,d,s]

    // d_out doubles as scratch for the 4 projection weights until out_mfma.
    unsigned short* Wt = (unsigned short*)d_out;

    // If workspace has a 4th buffer (32 MiB), prep Wo^T up front in the same
    // launch and skip the mid-pipeline prep. Else: proven 2-launch path
    // (Wo^T into Kf after attn, when Kf is dead).
    const bool bigws = ws_size >= 4 * PER * sizeof(unsigned short);

    if (bigws) {
        unsigned short* Wot = wsh + 3 * PER;
        dim3 gw(8, 8, 5);
        prep_w<<<gw, 256, 0, stream>>>(Wq, Wk, Wkb, Wv, Wo, Wt, Wot);

        dim3 gp((B_ * S_) / 128, H_ / 128, 3);  // 64 x 4 x 3
        proj_all<<<gp, 256, 0, stream>>>(q, k, v, k_b, Wt, bq, bk, bkb, bv,
                                         Qf, Kf, Vf);

        dim3 ga(S_ / 64, NH_, B_);              // 32 x 8 x 4 = 1024 blocks
        attn_mfma<<<ga, 256, 0, stream>>>(Qf, Kf, Vf, msk);

        dim3 go((B_ * S_) / 128, H_ / 64, 1);   // 64 x 8 = 512 blocks
        out_mfma<<<go, 256, 0, stream>>>(Qf, Wot, bo, out);
    } else {
        dim3 gw(8, 8, 4);
        prep_w<<<gw, 256, 0, stream>>>(Wq, Wk, Wkb, Wv, Wo, Wt, nullptr);

        dim3 gp((B_ * S_) / 128, H_ / 128, 3);
        proj_all<<<gp, 256, 0, stream>>>(q, k, v, k_b, Wt, bq, bk, bkb, bv,
                                         Qf, Kf, Vf);

        dim3 ga(S_ / 64, NH_, B_);
        attn_mfma<<<ga, 256, 0, stream>>>(Qf, Kf, Vf, msk);

        // Kf is dead after attn: reuse it for transposed Wo (z=0 path).
        dim3 gw1(8, 8, 1);
        prep_w<<<gw1, 256, 0, stream>>>(Wo, Wo, Wo, Wo, Wo, Kf, nullptr);

        dim3 go((B_ * S_) / 128, H_ / 64, 1);
        out_mfma<<<go, 256, 0, stream>>>(Qf, Kf, bo, out);
    }
}